// Round 4
// baseline (1556.252 us; speedup 1.0000x reference)
//
#include <hip/hip_runtime.h>
#include <stdint.h>
#include <math.h>

#define HIDN 512
#define NHEAD 4
#define DHEAD 128
#define BATCH 16
#define SEQ 1024
#define NNODE 1026
#define MROWS (BATCH * NNODE)   // 16416
#define MPAD 16512              // 129 * 128
#define MTOK (BATCH * SEQ)      // 16384
#define FFD 2048
#define FCH 2048                // FFN row chunk

typedef short bf16x8 __attribute__((ext_vector_type(8)));
typedef float f32x4 __attribute__((ext_vector_type(4)));

__device__ __forceinline__ float bf2f(ushort u) {
    union { uint32_t i; float f; } v; v.i = ((uint32_t)u) << 16; return v.f;
}
__device__ __forceinline__ ushort f2bf(float f) {
    uint32_t x = __float_as_uint(f);
    return (ushort)((x + 0x7fffu + ((x >> 16) & 1u)) >> 16);
}

// ---------------------------------------------------------------- build nodes: fp32 in -> bf16 node buffer
__global__ __launch_bounds__(256) void k_build_nodes(
    const float* __restrict__ g, const float* __restrict__ tok,
    const float* __restrict__ l, ushort* __restrict__ nb)
{
    int idx = blockIdx.x * 256 + threadIdx.x;       // MPAD*HIDN total
    int r = idx >> 9, c = idx & 511;
    float u = 0.f;
    if (r < MROWS) {
        int b = r / NNODE;
        int n = r - b * NNODE;
        if (n == 0)            u = g[b * HIDN + c];
        else if (n <= SEQ)     u = tok[((size_t)b * SEQ + (n - 1)) * HIDN + c];
        else                   u = l[b * HIDN + c];
    }
    nb[idx] = f2bf(u);
}

// ---------------------------------------------------------------- fp32 -> bf16 flat convert
__global__ __launch_bounds__(256) void k_cvt(
    const float* __restrict__ in, ushort* __restrict__ out, int n)
{
    int idx = blockIdx.x * 256 + threadIdx.x;
    if (idx < n) out[idx] = f2bf(in[idx]);
}

// ---------------------------------------------------------------- transpose fp32 -> bf16
__global__ __launch_bounds__(256) void k_transpose(
    const float* __restrict__ in, ushort* __restrict__ out, int R, int C)
{
    __shared__ float t[32][33];
    int x = blockIdx.x * 32 + threadIdx.x;
    int y0 = blockIdx.y * 32;
    for (int dy = threadIdx.y; dy < 32; dy += 8)
        t[dy][threadIdx.x] = in[(size_t)(y0 + dy) * C + x];
    __syncthreads();
    int ox = y0 + threadIdx.x;
    int oy0 = blockIdx.x * 32;
    for (int dy = threadIdx.y; dy < 32; dy += 8)
        out[(size_t)(oy0 + dy) * R + ox] = f2bf(t[threadIdx.x][dy]);
}

// ---------------------------------------------------------------- MFMA GEMM (A: rowmaj MxK bf16, Bt: NxK rowmaj bf16)
// mode 0: Cf fp32 = A*B                      (writes guarded gm < mguard)
// mode 1: Cb bf16 = gelu(A*B + bias)
// mode 2: Cb bf16 = A*B + bias + res[node-remapped row]   (res bf16)
// amap: A row is token row (m_base+gm) remapped to node row
#define BM 128
#define BN 128
#define BK 64

__global__ __launch_bounds__(256) void k_gemm_bt(
    const ushort* __restrict__ A, const ushort* __restrict__ Bt,
    float* __restrict__ Cf, ushort* __restrict__ Cb,
    const float* __restrict__ bias, const ushort* __restrict__ res,
    int N, int K, int mode, int amap, int m_base, int mguard)
{
    __shared__ ushort sA[BM * BK];
    __shared__ ushort sB[BN * BK];
    int tid = threadIdx.x;
    int lane = tid & 63;
    int wave = tid >> 6;
    int wm = wave >> 1, wn = wave & 1;
    int m0 = blockIdx.y * BM;
    int n0 = blockIdx.x * BN;

    f32x4 acc[4][4];
#pragma unroll
    for (int i = 0; i < 4; ++i)
#pragma unroll
        for (int j = 0; j < 4; ++j) acc[i][j] = (f32x4){0.f, 0.f, 0.f, 0.f};

    int lr = lane >> 3;          // 0..7  sub-row within 8-row chunk
    int lc = (lane & 7) * 8;     // element col of 16B chunk

    for (int k0 = 0; k0 < K; k0 += BK) {
#pragma unroll
        for (int t = 0; t < 4; ++t) {
            int q = wave * 4 + t;            // 0..15 : 8-row chunk id
            int rr = q * 8 + lr;
            int grA = m0 + rr;
            if (amap) { int tr = m_base + grA; grA = tr + 2 * (tr >> 10) + 1; }
            const ushort* gpA = A + (size_t)grA * K + (k0 + lc);
            __builtin_amdgcn_global_load_lds(
                (const __attribute__((address_space(1))) void*)gpA,
                (__attribute__((address_space(3))) void*)&sA[q * 512], 16, 0, 0);
            int grB = n0 + rr;
            const ushort* gpB = Bt + (size_t)grB * K + (k0 + lc);
            __builtin_amdgcn_global_load_lds(
                (const __attribute__((address_space(1))) void*)gpB,
                (__attribute__((address_space(3))) void*)&sB[q * 512], 16, 0, 0);
        }
        __syncthreads();
#pragma unroll
        for (int kk = 0; kk < BK; kk += 32) {
            int kcol = kk + (lane >> 4) * 8;
            int ar = wm * 64 + (lane & 15);
            int br = wn * 64 + (lane & 15);
            bf16x8 af[4], bfr[4];
#pragma unroll
            for (int i = 0; i < 4; ++i)
                af[i] = *reinterpret_cast<const bf16x8*>(&sA[(ar + i * 16) * BK + kcol]);
#pragma unroll
            for (int j = 0; j < 4; ++j)
                bfr[j] = *reinterpret_cast<const bf16x8*>(&sB[(br + j * 16) * BK + kcol]);
#pragma unroll
            for (int i = 0; i < 4; ++i)
#pragma unroll
                for (int j = 0; j < 4; ++j)
                    acc[i][j] = __builtin_amdgcn_mfma_f32_16x16x32_bf16(af[i], bfr[j], acc[i][j], 0, 0, 0);
        }
        __syncthreads();
    }

    int rb = (lane >> 4) * 4;
    int cb = lane & 15;
#pragma unroll
    for (int i = 0; i < 4; ++i) {
#pragma unroll
        for (int j = 0; j < 4; ++j) {
            int gn = n0 + wn * 64 + j * 16 + cb;
#pragma unroll
            for (int rg = 0; rg < 4; ++rg) {
                int gm = m0 + wm * 64 + i * 16 + rb + rg;
                if (gm >= mguard) continue;
                float v = acc[i][j][rg];
                if (mode == 0) {
                    Cf[(size_t)gm * N + gn] = v;
                } else if (mode == 1) {
                    v += bias[gn];
                    v = 0.5f * v * (1.f + erff(v * 0.70710678118654752f));
                    Cb[(size_t)gm * N + gn] = f2bf(v);
                } else {
                    int tr = m_base + gm;
                    int nrow = tr + 2 * (tr >> 10) + 1;
                    v += bias[gn] + bf2f(res[(size_t)nrow * HIDN + gn]);
                    Cb[(size_t)gm * N + gn] = f2bf(v);
                }
            }
        }
    }
}

// ---------------------------------------------------------------- sq/sk per node row (P fp32, a fp32)
__global__ __launch_bounds__(256) void k_sqsk(
    const float* __restrict__ P, const float* __restrict__ a,
    float* __restrict__ sq, float* __restrict__ sk)
{
    int wave = threadIdx.x >> 6, lane = threadIdx.x & 63;
    int row = blockIdx.x * 4 + wave;
    if (row >= MROWS) return;
    int hh = lane >> 4;
    int o0 = lane * 8;
    int dl = o0 & 127;
    const float* p = P + (size_t)row * HIDN + o0;
    const float* a1 = a + hh * 256 + dl;
    const float* a2 = a1 + 128;
    float s1 = 0.f, s2 = 0.f;
#pragma unroll
    for (int d = 0; d < 8; ++d) {
        float pv = p[d];
        s1 += pv * a1[d];
        s2 += pv * a2[d];
    }
#pragma unroll
    for (int off = 8; off; off >>= 1) {
        s1 += __shfl_xor(s1, off);
        s2 += __shfl_xor(s2, off);
    }
    if ((lane & 15) == 0) {
        sq[row * 4 + hh] = s1;
        sk[row * 4 + hh] = s2;
    }
}

// ---------------------------------------------------------------- token attention + elu + residual + LN (1 wave / token)
__global__ __launch_bounds__(64) void k_attn_token(
    const float* __restrict__ P, const float* __restrict__ sq, const float* __restrict__ sk,
    const float* __restrict__ am, const int* __restrict__ last,
    const float* __restrict__ gam, const float* __restrict__ bet,
    ushort* __restrict__ nb)
{
    int tokid = blockIdx.x;
    int b = tokid >> 10, i = tokid & 1023;
    int lane = threadIdx.x;
    int hh = lane >> 4;
    int base = b * NNODE;
    int qrow = base + 1 + i;

    // fixed 13-slot key list (slot0: global node, 1..11: window, 12: local node)
    int kr[13];
    int val[13];
    int rowok = am[b * SEQ + i] > 0.f ? 1 : 0;
    kr[0] = base; val[0] = rowok;
#pragma unroll
    for (int s = 0; s < 11; ++s) {
        int t = i - 5 + s;
        int inb = (t >= 0) && (t <= SEQ - 1);
        int tt = inb ? t : 0;
        int v = inb && rowok && (am[b * SEQ + tt] > 0.f);
        kr[1 + s] = base + 1 + tt;
        val[1 + s] = v;
    }
    kr[12] = base + SEQ + 1;
    val[12] = (rowok && (i >= last[b])) ? 1 : 0;

    float sqv = sq[qrow * 4 + hh];
    float sc[13];
    float mx = -1e30f;
#pragma unroll
    for (int t = 0; t < 13; ++t) {
        float s = 0.f;
        if (val[t]) {
            s = sqv + sk[kr[t] * 4 + hh];
            s = s >= 0.f ? s : 0.2f * s;
            mx = fmaxf(mx, s);
        }
        sc[t] = s;
    }
    float den = 0.f;
#pragma unroll
    for (int t = 0; t < 13; ++t) {
        float ev = 0.f;
        if (val[t]) ev = expf(sc[t] - mx);
        sc[t] = ev; den += ev;
    }
    float inv = (den > 1e-30f && den < 1e30f) ? 1.f / den : 0.f;

    int o0 = lane * 8;
    float accv[8] = {0.f, 0.f, 0.f, 0.f, 0.f, 0.f, 0.f, 0.f};
#pragma unroll
    for (int t = 0; t < 13; ++t) {
        if (val[t]) {
            float wgt = sc[t] * inv;
            const float* pv = P + (size_t)kr[t] * HIDN + o0;
#pragma unroll
            for (int d = 0; d < 8; ++d) accv[d] += wgt * pv[d];
        }
    }

    ushort* nrow = nb + (size_t)qrow * HIDN + o0;
    float x[8], s1 = 0.f, s2 = 0.f;
#pragma unroll
    for (int d = 0; d < 8; ++d) {
        float v = accv[d];
        v = v > 0.f ? v : expf(v) - 1.f;   // elu
        v += bf2f(nrow[d]);                // residual (read-before-write, same thread)
        x[d] = v; s1 += v; s2 += v * v;
    }
#pragma unroll
    for (int off = 32; off; off >>= 1) { s1 += __shfl_xor(s1, off); s2 += __shfl_xor(s2, off); }
    float mean = s1 * (1.f / 512.f);
    float var = s2 * (1.f / 512.f) - mean * mean; var = fmaxf(var, 0.f);
    float rn = rsqrtf(var + 1e-5f);
#pragma unroll
    for (int d = 0; d < 8; ++d) {
        float y = (x[d] - mean) * rn * gam[o0 + d] + bet[o0 + d];
        nrow[d] = f2bf(y);
    }
}

// ---------------------------------------------------------------- global/local attention + elu + residual + LN
__global__ __launch_bounds__(256) void k_attn_gl(
    const float* __restrict__ P, const float* __restrict__ sq, const float* __restrict__ sk,
    const int* __restrict__ last,
    const float* __restrict__ gam, const float* __restrict__ bet,
    ushort* __restrict__ nb)
{
    __shared__ float e[NNODE * 4];
    __shared__ float red[1024];
    int blk = blockIdx.x, b = blk >> 1, isl = blk & 1;
    int base = b * NNODE;
    int qrow = base + (isl ? (SEQ + 1) : 0);
    int lastb = last[b];
    int tid = threadIdx.x;

    float sqh[4];
#pragma unroll
    for (int h = 0; h < 4; ++h) sqh[h] = sq[qrow * 4 + h];

    float mx[4] = {-1e30f, -1e30f, -1e30f, -1e30f};
    for (int j = tid; j < NNODE; j += 256) {
        bool ok = !isl || (j == 0 || j == SEQ + 1 || (j >= lastb + 1 && j <= SEQ));
        if (ok) {
#pragma unroll
            for (int h = 0; h < 4; ++h) {
                float s = sqh[h] + sk[(base + j) * 4 + h];
                s = s >= 0.f ? s : 0.2f * s;
                mx[h] = fmaxf(mx[h], s);
            }
        }
    }
#pragma unroll
    for (int h = 0; h < 4; ++h) red[tid * 4 + h] = mx[h];
    __syncthreads();
    for (int s = 128; s; s >>= 1) {
        if (tid < s) {
#pragma unroll
            for (int h = 0; h < 4; ++h)
                red[tid * 4 + h] = fmaxf(red[tid * 4 + h], red[(tid + s) * 4 + h]);
        }
        __syncthreads();
    }
#pragma unroll
    for (int h = 0; h < 4; ++h) mx[h] = red[h];
    __syncthreads();

    float sm[4] = {0.f, 0.f, 0.f, 0.f};
    for (int j = tid; j < NNODE; j += 256) {
        bool ok = !isl || (j == 0 || j == SEQ + 1 || (j >= lastb + 1 && j <= SEQ));
#pragma unroll
        for (int h = 0; h < 4; ++h) {
            float v = 0.f;
            if (ok) {
                float s = sqh[h] + sk[(base + j) * 4 + h];
                s = s >= 0.f ? s : 0.2f * s;
                v = expf(s - mx[h]);
            }
            e[j * 4 + h] = v;
            sm[h] += v;
        }
    }
#pragma unroll
    for (int h = 0; h < 4; ++h) red[tid * 4 + h] = sm[h];
    __syncthreads();
    for (int s = 128; s; s >>= 1) {
        if (tid < s) {
#pragma unroll
            for (int h = 0; h < 4; ++h) red[tid * 4 + h] += red[(tid + s) * 4 + h];
        }
        __syncthreads();
    }
    float inv[4];
#pragma unroll
    for (int h = 0; h < 4; ++h) {
        float den = red[h];
        inv[h] = (den > 1e-30f && den < 1e30f) ? 1.f / den : 0.f;
    }
    __syncthreads();

    float xv[2], s1 = 0.f, s2 = 0.f;
#pragma unroll
    for (int u = 0; u < 2; ++u) {
        int o = tid + u * 256;
        int h = o >> 7;
        float acc = 0.f;
        for (int j = 0; j < NNODE; ++j)
            acc += e[j * 4 + h] * P[(size_t)(base + j) * HIDN + o];
        acc *= inv[h];
        float v = acc > 0.f ? acc : expf(acc) - 1.f;
        v += bf2f(nb[(size_t)qrow * HIDN + o]);
        xv[u] = v; s1 += v; s2 += v * v;
    }
    red[tid] = s1; red[256 + tid] = s2;
    __syncthreads();
    for (int s = 128; s; s >>= 1) {
        if (tid < s) { red[tid] += red[tid + s]; red[256 + tid] += red[256 + tid + s]; }
        __syncthreads();
    }
    float mean = red[0] * (1.f / 512.f);
    float var = red[256] * (1.f / 512.f) - mean * mean; var = fmaxf(var, 0.f);
    float rn = rsqrtf(var + 1e-5f);
#pragma unroll
    for (int u = 0; u < 2; ++u) {
        int o = tid + u * 256;
        float y = (xv[u] - mean) * rn * gam[o] + bet[o];
        nb[(size_t)qrow * HIDN + o] = f2bf(y);
    }
}

// ---------------------------------------------------------------- FFN + out-LN for g/l rows (32 rows total), fp32 weights
__global__ __launch_bounds__(256) void k_ffn_gl(
    const ushort* __restrict__ nb,
    const float* __restrict__ w1, const float* __restrict__ b1,
    const float* __restrict__ w2, const float* __restrict__ b2,
    const float* __restrict__ og, const float* __restrict__ obt,
    float* __restrict__ out)
{
    __shared__ float xs[512];
    __shared__ float smid[2048];
    __shared__ float red[512];
    int blk = blockIdx.x, b = blk >> 1, isl = blk & 1;
    int idx = isl ? 2 : 0;
    size_t row = (size_t)b * NNODE + (isl ? SEQ + 1 : 0);
    int tid = threadIdx.x;
    xs[tid] = bf2f(nb[row * HIDN + tid]);
    xs[tid + 256] = bf2f(nb[row * HIDN + tid + 256]);
    __syncthreads();
    const float* W1 = w1 + (size_t)idx * HIDN * FFD;
    for (int u = 0; u < 8; ++u) {
        int m = tid + u * 256;
        float acc = 0.f;
        for (int i = 0; i < HIDN; ++i) acc += xs[i] * W1[(size_t)i * FFD + m];
        acc += b1[idx * FFD + m];
        smid[m] = 0.5f * acc * (1.f + erff(acc * 0.70710678118654752f));
    }
    __syncthreads();
    const float* W2 = w2 + (size_t)idx * FFD * HIDN;
    float xv[2], s1 = 0.f, s2 = 0.f;
#pragma unroll
    for (int u = 0; u < 2; ++u) {
        int o = tid + u * 256;
        float acc = 0.f;
        for (int m = 0; m < FFD; ++m) acc += smid[m] * W2[(size_t)m * HIDN + o];
        acc += b2[idx * HIDN + o] + xs[o];
        xv[u] = acc; s1 += acc; s2 += acc * acc;
    }
    red[tid] = s1;
    __syncthreads();
    for (int s = 128; s; s >>= 1) { if (tid < s) red[tid] += red[tid + s]; __syncthreads(); }
    float mean = red[0] * (1.f / 512.f);
    __syncthreads();
    red[tid] = s2;
    __syncthreads();
    for (int s = 128; s; s >>= 1) { if (tid < s) red[tid] += red[tid + s]; __syncthreads(); }
    float var = red[0] * (1.f / 512.f) - mean * mean; var = fmaxf(var, 0.f);
    float rn = rsqrtf(var + 1e-5f);
    size_t obase = isl ? ((size_t)8192 + (size_t)MTOK * HIDN + (size_t)b * HIDN)
                       : ((size_t)b * HIDN);
#pragma unroll
    for (int u = 0; u < 2; ++u) {
        int o = tid + u * 256;
        float y = (xv[u] - mean) * rn * og[idx * HIDN + o] + obt[idx * HIDN + o];
        out[obase + o] = y;
    }
}

// ---------------------------------------------------------------- rowwise LN: bf16 in -> fp32 out (tokens)
__global__ __launch_bounds__(64) void k_ln_rows(
    const ushort* __restrict__ X, const float* __restrict__ gam,
    const float* __restrict__ bet, float* __restrict__ out)
{
    int row = blockIdx.x, lane = threadIdx.x;
    const ushort* x = X + (size_t)row * HIDN + lane * 8;
    float v[8], s1 = 0.f, s2 = 0.f;
#pragma unroll
    for (int d = 0; d < 8; ++d) { v[d] = bf2f(x[d]); s1 += v[d]; s2 += v[d] * v[d]; }
#pragma unroll
    for (int off = 32; off; off >>= 1) { s1 += __shfl_xor(s1, off); s2 += __shfl_xor(s2, off); }
    float mean = s1 * (1.f / 512.f);
    float var = s2 * (1.f / 512.f) - mean * mean; var = fmaxf(var, 0.f);
    float rn = rsqrtf(var + 1e-5f);
    int o0 = lane * 8;
    float* o = out + (size_t)row * HIDN + o0;
#pragma unroll
    for (int d = 0; d < 8; ++d)
        o[d] = (v[d] - mean) * rn * gam[o0 + d] + bet[o0 + d];
}

// ================================================================ launch
extern "C" void kernel_launch(void* const* d_in, const int* in_sizes, int n_in,
                              void* d_out, int out_size, void* d_ws, size_t ws_size,
                              hipStream_t stream)
{
    (void)in_sizes; (void)n_in; (void)out_size; (void)ws_size;
    const float* g_emb   = (const float*)d_in[0];
    const float* tok_emb = (const float*)d_in[1];
    const float* l_emb   = (const float*)d_in[2];
    const float* am      = (const float*)d_in[3];
    const int*   last    = (const int*)d_in[4];
    const float* gat_W   = (const float*)d_in[5];
    const float* gat_a   = (const float*)d_in[6];
    const float* ln_g    = (const float*)d_in[7];
    const float* ln_b    = (const float*)d_in[8];
    const float* ffn_w1  = (const float*)d_in[9];
    const float* ffn_b1  = (const float*)d_in[10];
    const float* ffn_w2  = (const float*)d_in[11];
    const float* ffn_b2  = (const float*)d_in[12];
    const float* oln_g   = (const float*)d_in[13];
    const float* oln_b   = (const float*)d_in[14];
    float* out = (float*)d_out;

    // workspace layout — ~31.7 MiB. every region fully written before read.
    char* w = (char*)d_ws;
    ushort* nodes_b = (ushort*)w; w += (size_t)MPAD * HIDN * 2;   // 16.9 MB  bf16 node state
    ushort* Hmid    = (ushort*)w; w += (size_t)FCH * FFD * 2;     //  8.4 MB
    ushort* Obuf    = (ushort*)w; w += (size_t)FCH * HIDN * 2;    //  2.1 MB
    ushort* w1t     = (ushort*)w; w += (size_t)FFD * HIDN * 2;    //  2.1 MB
    ushort* w2t     = (ushort*)w; w += (size_t)FFD * HIDN * 2;    //  2.1 MB
    ushort* gatWb   = (ushort*)w; w += (size_t)2 * HIDN * HIDN * 2; // 1.0 MB
    float*  sqb     = (float*)w;  w += (size_t)MPAD * 4 * 4;      //  0.26 MB
    float*  skb     = (float*)w;  w += (size_t)MPAD * 4 * 4;      //  0.26 MB

    // P (node projections, MROWS x 512 fp32) aliases d_out: exactly out_size
    // floats, dead before the first output write.
    float* P = out;

    k_build_nodes<<<MPAD * HIDN / 256, 256, 0, stream>>>(g_emb, tok_emb, l_emb, nodes_b);
    k_cvt<<<(2 * HIDN * HIDN) / 256, 256, 0, stream>>>(gat_W, gatWb, 2 * HIDN * HIDN);
    // w1[1] (512x2048) -> w1t (2048x512); w2[1] (2048x512) -> w2t (512x2048)
    k_transpose<<<dim3(FFD / 32, HIDN / 32), dim3(32, 8), 0, stream>>>(ffn_w1 + (size_t)HIDN * FFD, w1t, HIDN, FFD);
    k_transpose<<<dim3(HIDN / 32, FFD / 32), dim3(32, 8), 0, stream>>>(ffn_w2 + (size_t)FFD * HIDN, w2t, FFD, HIDN);

    for (int k = 0; k < 2; ++k) {
        k_gemm_bt<<<dim3(HIDN / BN, MPAD / BM), 256, 0, stream>>>(
            nodes_b, gatWb + (size_t)k * HIDN * HIDN, P, nullptr, nullptr, nullptr,
            HIDN, HIDN, 0, 0, 0, MROWS);
        k_sqsk<<<MROWS / 4, 256, 0, stream>>>(P, gat_a + k * NHEAD * 2 * DHEAD, sqb, skb);
        k_attn_token<<<MTOK, 64, 0, stream>>>(P, sqb, skb, am, last,
                                              ln_g + k * HIDN, ln_b + k * HIDN, nodes_b);
        k_attn_gl<<<BATCH * 2, 256, 0, stream>>>(P, sqb, skb, last,
                                                 ln_g + k * HIDN, ln_b + k * HIDN, nodes_b);
    }

    // P (= d_out) dead from here; outputs written below.
    k_ffn_gl<<<BATCH * 2, 256, 0, stream>>>(nodes_b, ffn_w1, ffn_b1, ffn_w2, ffn_b2, oln_g, oln_b, out);

    for (int c = 0; c < MTOK / FCH; ++c) {
        int mb = c * FCH;
        k_gemm_bt<<<dim3(FFD / BN, FCH / BM), 256, 0, stream>>>(
            nodes_b, w1t, nullptr, Hmid, ffn_b1 + FFD, nullptr, FFD, HIDN, 1, 1, mb, FCH);
        k_gemm_bt<<<dim3(HIDN / BN, FCH / BM), 256, 0, stream>>>(
            Hmid, w2t, nullptr, Obuf, ffn_b2 + HIDN, nodes_b, HIDN, FFD, 2, 0, mb, FCH);
        k_ln_rows<<<FCH, 64, 0, stream>>>(Obuf, oln_g + HIDN, oln_b + HIDN,
                                          out + 8192 + (size_t)mb * HIDN);
    }
}

// Round 5
// 1277.183 us; speedup vs baseline: 1.2185x; 1.2185x over previous
//
#include <hip/hip_runtime.h>
#include <stdint.h>
#include <math.h>

#define HIDN 512
#define NHEAD 4
#define DHEAD 128
#define BATCH 16
#define SEQ 1024
#define NNODE 1026
#define MROWS (BATCH * NNODE)   // 16416
#define MPAD 16512              // 129 * 128
#define MTOK (BATCH * SEQ)      // 16384
#define FFD 2048
#define FCH 2048                // FFN row chunk

typedef short bf16x8 __attribute__((ext_vector_type(8)));
typedef float f32x4 __attribute__((ext_vector_type(4)));

__device__ __forceinline__ float bf2f(ushort u) {
    union { uint32_t i; float f; } v; v.i = ((uint32_t)u) << 16; return v.f;
}
__device__ __forceinline__ ushort f2bf(float f) {
    uint32_t x = __float_as_uint(f);
    return (ushort)((x + 0x7fffu + ((x >> 16) & 1u)) >> 16);
}

// ---------------------------------------------------------------- build nodes: fp32 in -> bf16 node buffer
__global__ __launch_bounds__(256) void k_build_nodes(
    const float* __restrict__ g, const float* __restrict__ tok,
    const float* __restrict__ l, ushort* __restrict__ nb)
{
    int idx = blockIdx.x * 256 + threadIdx.x;       // MPAD*HIDN total
    int r = idx >> 9, c = idx & 511;
    float u = 0.f;
    if (r < MROWS) {
        int b = r / NNODE;
        int n = r - b * NNODE;
        if (n == 0)            u = g[b * HIDN + c];
        else if (n <= SEQ)     u = tok[((size_t)b * SEQ + (n - 1)) * HIDN + c];
        else                   u = l[b * HIDN + c];
    }
    nb[idx] = f2bf(u);
}

// ---------------------------------------------------------------- fp32 -> bf16 flat convert
__global__ __launch_bounds__(256) void k_cvt(
    const float* __restrict__ in, ushort* __restrict__ out, int n)
{
    int idx = blockIdx.x * 256 + threadIdx.x;
    if (idx < n) out[idx] = f2bf(in[idx]);
}

// ---------------------------------------------------------------- transpose fp32 -> bf16
__global__ __launch_bounds__(256) void k_transpose(
    const float* __restrict__ in, ushort* __restrict__ out, int R, int C)
{
    __shared__ float t[32][33];
    int x = blockIdx.x * 32 + threadIdx.x;
    int y0 = blockIdx.y * 32;
    for (int dy = threadIdx.y; dy < 32; dy += 8)
        t[dy][threadIdx.x] = in[(size_t)(y0 + dy) * C + x];
    __syncthreads();
    int ox = y0 + threadIdx.x;
    int oy0 = blockIdx.x * 32;
    for (int dy = threadIdx.y; dy < 32; dy += 8)
        out[(size_t)(oy0 + dy) * R + ox] = f2bf(t[threadIdx.x][dy]);
}

// ---------------------------------------------------------------- MFMA GEMM (A: rowmaj MxK bf16, Bt: NxK rowmaj bf16)
// mode 0: Cf fp32 = A*B                      (writes guarded gm < mguard)
// mode 1: Cb bf16 = gelu(A*B + bias)
// mode 2: Cb bf16 = A*B + bias + res[node-remapped row]   (res bf16)
// amap: A row is token row (m_base+gm) remapped to node row
#define BM 128
#define BN 128
#define BK 64

__global__ __launch_bounds__(256) void k_gemm_bt(
    const ushort* __restrict__ A, const ushort* __restrict__ Bt,
    float* __restrict__ Cf, ushort* __restrict__ Cb,
    const float* __restrict__ bias, const ushort* __restrict__ res,
    int N, int K, int mode, int amap, int m_base, int mguard)
{
    __shared__ ushort sA[BM * BK];
    __shared__ ushort sB[BN * BK];
    int tid = threadIdx.x;
    int lane = tid & 63;
    int wave = tid >> 6;
    int wm = wave >> 1, wn = wave & 1;
    int m0 = blockIdx.y * BM;
    int n0 = blockIdx.x * BN;

    f32x4 acc[4][4];
#pragma unroll
    for (int i = 0; i < 4; ++i)
#pragma unroll
        for (int j = 0; j < 4; ++j) acc[i][j] = (f32x4){0.f, 0.f, 0.f, 0.f};

    int lr = lane >> 3;          // 0..7  sub-row within 8-row chunk
    int lc = (lane & 7) * 8;     // element col of 16B chunk

    for (int k0 = 0; k0 < K; k0 += BK) {
#pragma unroll
        for (int t = 0; t < 4; ++t) {
            int q = wave * 4 + t;            // 0..15 : 8-row chunk id
            int rr = q * 8 + lr;
            int grA = m0 + rr;
            if (amap) { int tr = m_base + grA; grA = tr + 2 * (tr >> 10) + 1; }
            const ushort* gpA = A + (size_t)grA * K + (k0 + lc);
            __builtin_amdgcn_global_load_lds(
                (const __attribute__((address_space(1))) void*)gpA,
                (__attribute__((address_space(3))) void*)&sA[q * 512], 16, 0, 0);
            int grB = n0 + rr;
            const ushort* gpB = Bt + (size_t)grB * K + (k0 + lc);
            __builtin_amdgcn_global_load_lds(
                (const __attribute__((address_space(1))) void*)gpB,
                (__attribute__((address_space(3))) void*)&sB[q * 512], 16, 0, 0);
        }
        __syncthreads();
#pragma unroll
        for (int kk = 0; kk < BK; kk += 32) {
            int kcol = kk + (lane >> 4) * 8;
            int ar = wm * 64 + (lane & 15);
            int br = wn * 64 + (lane & 15);
            bf16x8 af[4], bfr[4];
#pragma unroll
            for (int i = 0; i < 4; ++i)
                af[i] = *reinterpret_cast<const bf16x8*>(&sA[(ar + i * 16) * BK + kcol]);
#pragma unroll
            for (int j = 0; j < 4; ++j)
                bfr[j] = *reinterpret_cast<const bf16x8*>(&sB[(br + j * 16) * BK + kcol]);
#pragma unroll
            for (int i = 0; i < 4; ++i)
#pragma unroll
                for (int j = 0; j < 4; ++j)
                    acc[i][j] = __builtin_amdgcn_mfma_f32_16x16x32_bf16(af[i], bfr[j], acc[i][j], 0, 0, 0);
        }
        __syncthreads();
    }

    int rb = (lane >> 4) * 4;
    int cb = lane & 15;
#pragma unroll
    for (int i = 0; i < 4; ++i) {
#pragma unroll
        for (int j = 0; j < 4; ++j) {
            int gn = n0 + wn * 64 + j * 16 + cb;
#pragma unroll
            for (int rg = 0; rg < 4; ++rg) {
                int gm = m0 + wm * 64 + i * 16 + rb + rg;
                if (gm >= mguard) continue;
                float v = acc[i][j][rg];
                if (mode == 0) {
                    Cf[(size_t)gm * N + gn] = v;
                } else if (mode == 1) {
                    v += bias[gn];
                    v = 0.5f * v * (1.f + erff(v * 0.70710678118654752f));
                    Cb[(size_t)gm * N + gn] = f2bf(v);
                } else {
                    int tr = m_base + gm;
                    int nrow = tr + 2 * (tr >> 10) + 1;
                    v += bias[gn] + bf2f(res[(size_t)nrow * HIDN + gn]);
                    Cb[(size_t)gm * N + gn] = f2bf(v);
                }
            }
        }
    }
}

// ---------------------------------------------------------------- sq/sk per node row (P fp32, a fp32)
__global__ __launch_bounds__(256) void k_sqsk(
    const float* __restrict__ P, const float* __restrict__ a,
    float* __restrict__ sq, float* __restrict__ sk)
{
    int wave = threadIdx.x >> 6, lane = threadIdx.x & 63;
    int row = blockIdx.x * 4 + wave;
    if (row >= MROWS) return;
    int hh = lane >> 4;
    int o0 = lane * 8;
    int dl = o0 & 127;
    const float* p = P + (size_t)row * HIDN + o0;
    const float* a1 = a + hh * 256 + dl;
    const float* a2 = a1 + 128;
    float s1 = 0.f, s2 = 0.f;
#pragma unroll
    for (int d = 0; d < 8; ++d) {
        float pv = p[d];
        s1 += pv * a1[d];
        s2 += pv * a2[d];
    }
#pragma unroll
    for (int off = 8; off; off >>= 1) {
        s1 += __shfl_xor(s1, off);
        s2 += __shfl_xor(s2, off);
    }
    if ((lane & 15) == 0) {
        sq[row * 4 + hh] = s1;
        sk[row * 4 + hh] = s2;
    }
}

// ---------------------------------------------------------------- token attention + elu + residual + LN (1 wave / token)
__global__ __launch_bounds__(64) void k_attn_token(
    const float* __restrict__ P, const float* __restrict__ sq, const float* __restrict__ sk,
    const float* __restrict__ am, const int* __restrict__ last,
    const float* __restrict__ gam, const float* __restrict__ bet,
    ushort* __restrict__ nb)
{
    int tokid = blockIdx.x;
    int b = tokid >> 10, i = tokid & 1023;
    int lane = threadIdx.x;
    int hh = lane >> 4;
    int base = b * NNODE;
    int qrow = base + 1 + i;

    // fixed 13-slot key list (slot0: global node, 1..11: window, 12: local node)
    int kr[13];
    int val[13];
    int rowok = am[b * SEQ + i] > 0.f ? 1 : 0;
    kr[0] = base; val[0] = rowok;
#pragma unroll
    for (int s = 0; s < 11; ++s) {
        int t = i - 5 + s;
        int inb = (t >= 0) && (t <= SEQ - 1);
        int tt = inb ? t : 0;
        int v = inb && rowok && (am[b * SEQ + tt] > 0.f);
        kr[1 + s] = base + 1 + tt;
        val[1 + s] = v;
    }
    kr[12] = base + SEQ + 1;
    val[12] = (rowok && (i >= last[b])) ? 1 : 0;

    float sqv = sq[qrow * 4 + hh];
    float sc[13];
    float mx = -1e30f;
#pragma unroll
    for (int t = 0; t < 13; ++t) {
        float s = 0.f;
        if (val[t]) {
            s = sqv + sk[kr[t] * 4 + hh];
            s = s >= 0.f ? s : 0.2f * s;
            mx = fmaxf(mx, s);
        }
        sc[t] = s;
    }
    float den = 0.f;
#pragma unroll
    for (int t = 0; t < 13; ++t) {
        float ev = 0.f;
        if (val[t]) ev = expf(sc[t] - mx);
        sc[t] = ev; den += ev;
    }
    float inv = (den > 1e-30f && den < 1e30f) ? 1.f / den : 0.f;

    int o0 = lane * 8;
    float accv[8] = {0.f, 0.f, 0.f, 0.f, 0.f, 0.f, 0.f, 0.f};
#pragma unroll
    for (int t = 0; t < 13; ++t) {
        if (val[t]) {
            float wgt = sc[t] * inv;
            const float* pv = P + (size_t)kr[t] * HIDN + o0;
#pragma unroll
            for (int d = 0; d < 8; ++d) accv[d] += wgt * pv[d];
        }
    }

    ushort* nrow = nb + (size_t)qrow * HIDN + o0;
    float x[8], s1 = 0.f, s2 = 0.f;
#pragma unroll
    for (int d = 0; d < 8; ++d) {
        float v = accv[d];
        v = v > 0.f ? v : expf(v) - 1.f;   // elu
        v += bf2f(nrow[d]);                // residual (read-before-write, same thread)
        x[d] = v; s1 += v; s2 += v * v;
    }
#pragma unroll
    for (int off = 32; off; off >>= 1) { s1 += __shfl_xor(s1, off); s2 += __shfl_xor(s2, off); }
    float mean = s1 * (1.f / 512.f);
    float var = s2 * (1.f / 512.f) - mean * mean; var = fmaxf(var, 0.f);
    float rn = rsqrtf(var + 1e-5f);
#pragma unroll
    for (int d = 0; d < 8; ++d) {
        float y = (x[d] - mean) * rn * gam[o0 + d] + bet[o0 + d];
        nrow[d] = f2bf(y);
    }
}

// ---------------------------------------------------------------- global/local attention + elu + residual + LN
__global__ __launch_bounds__(256) void k_attn_gl(
    const float* __restrict__ P, const float* __restrict__ sq, const float* __restrict__ sk,
    const int* __restrict__ last,
    const float* __restrict__ gam, const float* __restrict__ bet,
    ushort* __restrict__ nb)
{
    __shared__ float e[NNODE * 4];
    __shared__ float red[1024];
    int blk = blockIdx.x, b = blk >> 1, isl = blk & 1;
    int base = b * NNODE;
    int qrow = base + (isl ? (SEQ + 1) : 0);
    int lastb = last[b];
    int tid = threadIdx.x;

    float sqh[4];
#pragma unroll
    for (int h = 0; h < 4; ++h) sqh[h] = sq[qrow * 4 + h];

    float mx[4] = {-1e30f, -1e30f, -1e30f, -1e30f};
    for (int j = tid; j < NNODE; j += 256) {
        bool ok = !isl || (j == 0 || j == SEQ + 1 || (j >= lastb + 1 && j <= SEQ));
        if (ok) {
#pragma unroll
            for (int h = 0; h < 4; ++h) {
                float s = sqh[h] + sk[(base + j) * 4 + h];
                s = s >= 0.f ? s : 0.2f * s;
                mx[h] = fmaxf(mx[h], s);
            }
        }
    }
#pragma unroll
    for (int h = 0; h < 4; ++h) red[tid * 4 + h] = mx[h];
    __syncthreads();
    for (int s = 128; s; s >>= 1) {
        if (tid < s) {
#pragma unroll
            for (int h = 0; h < 4; ++h)
                red[tid * 4 + h] = fmaxf(red[tid * 4 + h], red[(tid + s) * 4 + h]);
        }
        __syncthreads();
    }
#pragma unroll
    for (int h = 0; h < 4; ++h) mx[h] = red[h];
    __syncthreads();

    float sm[4] = {0.f, 0.f, 0.f, 0.f};
    for (int j = tid; j < NNODE; j += 256) {
        bool ok = !isl || (j == 0 || j == SEQ + 1 || (j >= lastb + 1 && j <= SEQ));
#pragma unroll
        for (int h = 0; h < 4; ++h) {
            float v = 0.f;
            if (ok) {
                float s = sqh[h] + sk[(base + j) * 4 + h];
                s = s >= 0.f ? s : 0.2f * s;
                v = expf(s - mx[h]);
            }
            e[j * 4 + h] = v;
            sm[h] += v;
        }
    }
#pragma unroll
    for (int h = 0; h < 4; ++h) red[tid * 4 + h] = sm[h];
    __syncthreads();
    for (int s = 128; s; s >>= 1) {
        if (tid < s) {
#pragma unroll
            for (int h = 0; h < 4; ++h) red[tid * 4 + h] += red[(tid + s) * 4 + h];
        }
        __syncthreads();
    }
    float inv[4];
#pragma unroll
    for (int h = 0; h < 4; ++h) {
        float den = red[h];
        inv[h] = (den > 1e-30f && den < 1e30f) ? 1.f / den : 0.f;
    }
    __syncthreads();

    float xv[2], s1 = 0.f, s2 = 0.f;
#pragma unroll
    for (int u = 0; u < 2; ++u) {
        int o = tid + u * 256;
        int h = o >> 7;
        float acc = 0.f;
        for (int j = 0; j < NNODE; ++j)
            acc += e[j * 4 + h] * P[(size_t)(base + j) * HIDN + o];
        acc *= inv[h];
        float v = acc > 0.f ? acc : expf(acc) - 1.f;
        v += bf2f(nb[(size_t)qrow * HIDN + o]);
        xv[u] = v; s1 += v; s2 += v * v;
    }
    red[tid] = s1; red[256 + tid] = s2;
    __syncthreads();
    for (int s = 128; s; s >>= 1) {
        if (tid < s) { red[tid] += red[tid + s]; red[256 + tid] += red[256 + tid + s]; }
        __syncthreads();
    }
    float mean = red[0] * (1.f / 512.f);
    float var = red[256] * (1.f / 512.f) - mean * mean; var = fmaxf(var, 0.f);
    float rn = rsqrtf(var + 1e-5f);
#pragma unroll
    for (int u = 0; u < 2; ++u) {
        int o = tid + u * 256;
        float y = (xv[u] - mean) * rn * gam[o] + bet[o];
        nb[(size_t)qrow * HIDN + o] = f2bf(y);
    }
}

// ---------------------------------------------------------------- g/l FFN, parallel split version
// rw in [0,32): b = rw>>1, isl = rw&1; weight set idx = isl?2:0
// scratch (in Hmid region): pmid[32][8][2048] f32, mid[32][2048] f32, pout[32][8][512] f32

// stage 1: FFN1 partials over k-split p (i in [64p, 64p+64))
__global__ __launch_bounds__(256) void k_fgl1(
    const ushort* __restrict__ nb, const float* __restrict__ w1,
    float* __restrict__ pmid)
{
    __shared__ float xs[64];
    int p = blockIdx.x, rw = blockIdx.y;
    int b = rw >> 1, isl = rw & 1;
    int idx = isl ? 2 : 0;
    size_t nrow = (size_t)b * NNODE + (isl ? SEQ + 1 : 0);
    int tid = threadIdx.x;
    if (tid < 64) xs[tid] = bf2f(nb[nrow * HIDN + p * 64 + tid]);
    __syncthreads();
    const float* W1 = w1 + (size_t)idx * HIDN * FFD + (size_t)p * 64 * FFD;
    float acc[8] = {0.f, 0.f, 0.f, 0.f, 0.f, 0.f, 0.f, 0.f};
    for (int ii = 0; ii < 64; ++ii) {
        float xv = xs[ii];
        const float* wrow = W1 + (size_t)ii * FFD + tid;
#pragma unroll
        for (int u = 0; u < 8; ++u) acc[u] += xv * wrow[u * 256];
    }
    float* o = pmid + ((size_t)rw * 8 + p) * FFD + tid;
#pragma unroll
    for (int u = 0; u < 8; ++u) o[u * 256] = acc[u];
}

// stage 2: reduce partials + bias + gelu -> mid
__global__ __launch_bounds__(256) void k_fgl2(
    const float* __restrict__ pmid, const float* __restrict__ b1,
    float* __restrict__ mid)
{
    int g = blockIdx.x * 256 + threadIdx.x;   // 16384 threads, 4 elems each
    int e4 = g * 4;
    int rw = e4 >> 11;
    int m = e4 & 2047;
    int isl = rw & 1;
    int idx = isl ? 2 : 0;
#pragma unroll
    for (int d = 0; d < 4; ++d) {
        float s = 0.f;
#pragma unroll
        for (int p = 0; p < 8; ++p)
            s += pmid[((size_t)rw * 8 + p) * FFD + m + d];
        s += b1[idx * FFD + m + d];
        mid[(size_t)rw * FFD + m + d] = 0.5f * s * (1.f + erff(s * 0.70710678118654752f));
    }
}

// stage 3: FFN2 partials over m-split p (m in [256p, 256p+256))
__global__ __launch_bounds__(256) void k_fgl3(
    const float* __restrict__ mid, const float* __restrict__ w2,
    float* __restrict__ pout)
{
    __shared__ float ms[256];
    int p = blockIdx.x, rw = blockIdx.y;
    int isl = rw & 1;
    int idx = isl ? 2 : 0;
    int tid = threadIdx.x;
    ms[tid] = mid[(size_t)rw * FFD + p * 256 + tid];
    __syncthreads();
    const float* W2 = w2 + (size_t)idx * FFD * HIDN + (size_t)p * 256 * HIDN;
    float a0 = 0.f, a1 = 0.f;
    for (int mm = 0; mm < 256; ++mm) {
        float mv = ms[mm];
        const float* wrow = W2 + (size_t)mm * HIDN + tid;
        a0 += mv * wrow[0];
        a1 += mv * wrow[256];
    }
    float* o = pout + ((size_t)rw * 8 + p) * HIDN + tid;
    o[0] = a0;
    o[256] = a1;
}

// stage 4: reduce + bias + residual + out-LN + store
__global__ __launch_bounds__(256) void k_fgl4(
    const float* __restrict__ pout, const float* __restrict__ b2,
    const ushort* __restrict__ nb,
    const float* __restrict__ og, const float* __restrict__ obt,
    float* __restrict__ out)
{
    __shared__ float red[512];
    int rw = blockIdx.x;
    int b = rw >> 1, isl = rw & 1;
    int idx = isl ? 2 : 0;
    size_t nrow = (size_t)b * NNODE + (isl ? SEQ + 1 : 0);
    int tid = threadIdx.x;
    float xv[2], s1 = 0.f, s2 = 0.f;
#pragma unroll
    for (int u = 0; u < 2; ++u) {
        int o = tid + u * 256;
        float s = 0.f;
#pragma unroll
        for (int p = 0; p < 8; ++p)
            s += pout[((size_t)rw * 8 + p) * HIDN + o];
        s += b2[idx * HIDN + o] + bf2f(nb[nrow * HIDN + o]);
        xv[u] = s; s1 += s; s2 += s * s;
    }
    red[tid] = s1;
    __syncthreads();
    for (int s = 128; s; s >>= 1) { if (tid < s) red[tid] += red[tid + s]; __syncthreads(); }
    float mean = red[0] * (1.f / 512.f);
    __syncthreads();
    red[tid] = s2;
    __syncthreads();
    for (int s = 128; s; s >>= 1) { if (tid < s) red[tid] += red[tid + s]; __syncthreads(); }
    float var = red[0] * (1.f / 512.f) - mean * mean; var = fmaxf(var, 0.f);
    float rn = rsqrtf(var + 1e-5f);
    size_t obase = isl ? ((size_t)8192 + (size_t)MTOK * HIDN + (size_t)b * HIDN)
                       : ((size_t)b * HIDN);
#pragma unroll
    for (int u = 0; u < 2; ++u) {
        int o = tid + u * 256;
        out[obase + o] = (xv[u] - mean) * rn * og[idx * HIDN + o] + obt[idx * HIDN + o];
    }
}

// ---------------------------------------------------------------- rowwise LN: bf16 in -> fp32 out (tokens)
__global__ __launch_bounds__(64) void k_ln_rows(
    const ushort* __restrict__ X, const float* __restrict__ gam,
    const float* __restrict__ bet, float* __restrict__ out)
{
    int row = blockIdx.x, lane = threadIdx.x;
    const ushort* x = X + (size_t)row * HIDN + lane * 8;
    float v[8], s1 = 0.f, s2 = 0.f;
#pragma unroll
    for (int d = 0; d < 8; ++d) { v[d] = bf2f(x[d]); s1 += v[d]; s2 += v[d] * v[d]; }
#pragma unroll
    for (int off = 32; off; off >>= 1) { s1 += __shfl_xor(s1, off); s2 += __shfl_xor(s2, off); }
    float mean = s1 * (1.f / 512.f);
    float var = s2 * (1.f / 512.f) - mean * mean; var = fmaxf(var, 0.f);
    float rn = rsqrtf(var + 1e-5f);
    int o0 = lane * 8;
    float* o = out + (size_t)row * HIDN + o0;
#pragma unroll
    for (int d = 0; d < 8; ++d)
        o[d] = (v[d] - mean) * rn * gam[o0 + d] + bet[o0 + d];
}

// ================================================================ launch
extern "C" void kernel_launch(void* const* d_in, const int* in_sizes, int n_in,
                              void* d_out, int out_size, void* d_ws, size_t ws_size,
                              hipStream_t stream)
{
    (void)in_sizes; (void)n_in; (void)out_size; (void)ws_size;
    const float* g_emb   = (const float*)d_in[0];
    const float* tok_emb = (const float*)d_in[1];
    const float* l_emb   = (const float*)d_in[2];
    const float* am      = (const float*)d_in[3];
    const int*   last    = (const int*)d_in[4];
    const float* gat_W   = (const float*)d_in[5];
    const float* gat_a   = (const float*)d_in[6];
    const float* ln_g    = (const float*)d_in[7];
    const float* ln_b    = (const float*)d_in[8];
    const float* ffn_w1  = (const float*)d_in[9];
    const float* ffn_b1  = (const float*)d_in[10];
    const float* ffn_w2  = (const float*)d_in[11];
    const float* ffn_b2  = (const float*)d_in[12];
    const float* oln_g   = (const float*)d_in[13];
    const float* oln_b   = (const float*)d_in[14];
    float* out = (float*)d_out;

    // workspace layout — ~33.1 MiB (proven). every region fully written before read.
    char* w = (char*)d_ws;
    ushort* nodes_b = (ushort*)w; w += (size_t)MPAD * HIDN * 2;   // 16.9 MB  bf16 node state
    ushort* Hmid    = (ushort*)w; w += (size_t)FCH * FFD * 2;     //  8.4 MB
    ushort* Obuf    = (ushort*)w; w += (size_t)FCH * HIDN * 2;    //  2.1 MB
    ushort* w1t     = (ushort*)w; w += (size_t)FFD * HIDN * 2;    //  2.1 MB
    ushort* w2t     = (ushort*)w; w += (size_t)FFD * HIDN * 2;    //  2.1 MB
    ushort* gatWb   = (ushort*)w; w += (size_t)2 * HIDN * HIDN * 2; // 1.0 MB
    float*  sqb     = (float*)w;  w += (size_t)MPAD * 4 * 4;      //  0.26 MB
    float*  skb     = (float*)w;  w += (size_t)MPAD * 4 * 4;      //  0.26 MB

    // g/l FFN scratch lives inside Hmid (2.75 MB < 8.4 MB); Hmid is written
    // later by the token FFN chunks.
    float* pmid = (float*)Hmid;                       // 32*8*2048 f32 = 2 MB
    float* mid  = pmid + (size_t)32 * 8 * FFD;        // 32*2048 f32 = 256 KB
    float* pout = mid + (size_t)32 * FFD;             // 32*8*512 f32 = 512 KB

    // P (node projections, MROWS x 512 fp32) aliases d_out: exactly out_size
    // floats, dead before the first output write.
    float* P = out;

    k_build_nodes<<<MPAD * HIDN / 256, 256, 0, stream>>>(g_emb, tok_emb, l_emb, nodes_b);
    k_cvt<<<(2 * HIDN * HIDN) / 256, 256, 0, stream>>>(gat_W, gatWb, 2 * HIDN * HIDN);
    // w1[1] (512x2048) -> w1t (2048x512); w2[1] (2048x512) -> w2t (512x2048)
    k_transpose<<<dim3(FFD / 32, HIDN / 32), dim3(32, 8), 0, stream>>>(ffn_w1 + (size_t)HIDN * FFD, w1t, HIDN, FFD);
    k_transpose<<<dim3(HIDN / 32, FFD / 32), dim3(32, 8), 0, stream>>>(ffn_w2 + (size_t)FFD * HIDN, w2t, FFD, HIDN);

    for (int k = 0; k < 2; ++k) {
        k_gemm_bt<<<dim3(HIDN / BN, MPAD / BM), 256, 0, stream>>>(
            nodes_b, gatWb + (size_t)k * HIDN * HIDN, P, nullptr, nullptr, nullptr,
            HIDN, HIDN, 0, 0, 0, MROWS);
        k_sqsk<<<MROWS / 4, 256, 0, stream>>>(P, gat_a + k * NHEAD * 2 * DHEAD, sqb, skb);
        k_attn_token<<<MTOK, 64, 0, stream>>>(P, sqb, skb, am, last,
                                              ln_g + k * HIDN, ln_b + k * HIDN, nodes_b);
        k_attn_gl<<<BATCH * 2, 256, 0, stream>>>(P, sqb, skb, last,
                                                 ln_g + k * HIDN, ln_b + k * HIDN, nodes_b);
    }

    // g/l FFN (parallel split), scratch in Hmid — must precede token FFN chunks.
    k_fgl1<<<dim3(8, 32), 256, 0, stream>>>(nodes_b, ffn_w1, pmid);
    k_fgl2<<<64, 256, 0, stream>>>(pmid, ffn_b1, mid);
    k_fgl3<<<dim3(8, 32), 256, 0, stream>>>(mid, ffn_w2, pout);
    k_fgl4<<<32, 256, 0, stream>>>(pout, ffn_b2, nodes_b, oln_g, oln_b, out);

    // P (= d_out) dead from here (token outputs only).
    for (int c = 0; c < MTOK / FCH; ++c) {
        int mb = c * FCH;
        k_gemm_bt<<<dim3(FFD / BN, FCH / BM), 256, 0, stream>>>(
            nodes_b, w1t, nullptr, Hmid, ffn_b1 + FFD, nullptr, FFD, HIDN, 1, 1, mb, FCH);
        k_gemm_bt<<<dim3(HIDN / BN, FCH / BM), 256, 0, stream>>>(
            Hmid, w2t, nullptr, Obuf, ffn_b2 + HIDN, nodes_b, HIDN, FFD, 2, 0, mb, FCH);
        k_ln_rows<<<FCH, 64, 0, stream>>>(Obuf, oln_g + HIDN, oln_b + HIDN,
                                          out + 8192 + (size_t)mb * HIDN);
    }
}

// Round 6
// 1155.208 us; speedup vs baseline: 1.3472x; 1.1056x over previous
//
#include <hip/hip_runtime.h>
#include <stdint.h>
#include <math.h>

#define HIDN 512
#define NHEAD 4
#define DHEAD 128
#define BATCH 16
#define SEQ 1024
#define NNODE 1026
#define MROWS (BATCH * NNODE)   // 16416
#define MPAD 16512              // 129 * 128
#define MTOK (BATCH * SEQ)      // 16384
#define FFD 2048
#define FCH 2048                // FFN row chunk
#define JCH 114                 // gl-attn j-chunk (9 * 114 = 1026)

typedef short bf16x8 __attribute__((ext_vector_type(8)));
typedef float f32x4 __attribute__((ext_vector_type(4)));

__device__ __forceinline__ float bf2f(ushort u) {
    union { uint32_t i; float f; } v; v.i = ((uint32_t)u) << 16; return v.f;
}
__device__ __forceinline__ ushort f2bf(float f) {
    uint32_t x = __float_as_uint(f);
    return (ushort)((x + 0x7fffu + ((x >> 16) & 1u)) >> 16);
}

// ---------------------------------------------------------------- build nodes: fp32 in -> bf16 node buffer
__global__ __launch_bounds__(256) void k_build_nodes(
    const float* __restrict__ g, const float* __restrict__ tok,
    const float* __restrict__ l, ushort* __restrict__ nb)
{
    int idx = blockIdx.x * 256 + threadIdx.x;       // MPAD*HIDN total
    int r = idx >> 9, c = idx & 511;
    float u = 0.f;
    if (r < MROWS) {
        int b = r / NNODE;
        int n = r - b * NNODE;
        if (n == 0)            u = g[b * HIDN + c];
        else if (n <= SEQ)     u = tok[((size_t)b * SEQ + (n - 1)) * HIDN + c];
        else                   u = l[b * HIDN + c];
    }
    nb[idx] = f2bf(u);
}

// ---------------------------------------------------------------- fp32 -> bf16 flat convert
__global__ __launch_bounds__(256) void k_cvt(
    const float* __restrict__ in, ushort* __restrict__ out, int n)
{
    int idx = blockIdx.x * 256 + threadIdx.x;
    if (idx < n) out[idx] = f2bf(in[idx]);
}

// ---------------------------------------------------------------- transpose fp32 -> bf16
__global__ __launch_bounds__(256) void k_transpose(
    const float* __restrict__ in, ushort* __restrict__ out, int R, int C)
{
    __shared__ float t[32][33];
    int x = blockIdx.x * 32 + threadIdx.x;
    int y0 = blockIdx.y * 32;
    for (int dy = threadIdx.y; dy < 32; dy += 8)
        t[dy][threadIdx.x] = in[(size_t)(y0 + dy) * C + x];
    __syncthreads();
    int ox = y0 + threadIdx.x;
    int oy0 = blockIdx.x * 32;
    for (int dy = threadIdx.y; dy < 32; dy += 8)
        out[(size_t)(oy0 + dy) * R + ox] = f2bf(t[threadIdx.x][dy]);
}

// ---------------------------------------------------------------- MFMA GEMM (A: rowmaj MxK bf16, Bt: NxK rowmaj bf16)
// mode 0: Cf fp32 = A*B                      (writes guarded gm < mguard)
// mode 1: Cb bf16 = gelu(A*B + bias)
// mode 2: Cb bf16 = A*B + bias + res[node-remapped row]   (res bf16)
// amap: A row is token row (m_base+gm) remapped to node row
#define BM 128
#define BN 128
#define BK 64

__global__ __launch_bounds__(256) void k_gemm_bt(
    const ushort* __restrict__ A, const ushort* __restrict__ Bt,
    float* __restrict__ Cf, ushort* __restrict__ Cb,
    const float* __restrict__ bias, const ushort* __restrict__ res,
    int N, int K, int mode, int amap, int m_base, int mguard)
{
    __shared__ ushort sA[BM * BK];
    __shared__ ushort sB[BN * BK];
    int tid = threadIdx.x;
    int lane = tid & 63;
    int wave = tid >> 6;
    int wm = wave >> 1, wn = wave & 1;
    int m0 = blockIdx.y * BM;
    int n0 = blockIdx.x * BN;

    f32x4 acc[4][4];
#pragma unroll
    for (int i = 0; i < 4; ++i)
#pragma unroll
        for (int j = 0; j < 4; ++j) acc[i][j] = (f32x4){0.f, 0.f, 0.f, 0.f};

    int lr = lane >> 3;          // 0..7  sub-row within 8-row chunk
    int lc = (lane & 7) * 8;     // element col of 16B chunk

    for (int k0 = 0; k0 < K; k0 += BK) {
#pragma unroll
        for (int t = 0; t < 4; ++t) {
            int q = wave * 4 + t;            // 0..15 : 8-row chunk id
            int rr = q * 8 + lr;
            int grA = m0 + rr;
            if (amap) { int tr = m_base + grA; grA = tr + 2 * (tr >> 10) + 1; }
            const ushort* gpA = A + (size_t)grA * K + (k0 + lc);
            __builtin_amdgcn_global_load_lds(
                (const __attribute__((address_space(1))) void*)gpA,
                (__attribute__((address_space(3))) void*)&sA[q * 512], 16, 0, 0);
            int grB = n0 + rr;
            const ushort* gpB = Bt + (size_t)grB * K + (k0 + lc);
            __builtin_amdgcn_global_load_lds(
                (const __attribute__((address_space(1))) void*)gpB,
                (__attribute__((address_space(3))) void*)&sB[q * 512], 16, 0, 0);
        }
        __syncthreads();
#pragma unroll
        for (int kk = 0; kk < BK; kk += 32) {
            int kcol = kk + (lane >> 4) * 8;
            int ar = wm * 64 + (lane & 15);
            int br = wn * 64 + (lane & 15);
            bf16x8 af[4], bfr[4];
#pragma unroll
            for (int i = 0; i < 4; ++i)
                af[i] = *reinterpret_cast<const bf16x8*>(&sA[(ar + i * 16) * BK + kcol]);
#pragma unroll
            for (int j = 0; j < 4; ++j)
                bfr[j] = *reinterpret_cast<const bf16x8*>(&sB[(br + j * 16) * BK + kcol]);
#pragma unroll
            for (int i = 0; i < 4; ++i)
#pragma unroll
                for (int j = 0; j < 4; ++j)
                    acc[i][j] = __builtin_amdgcn_mfma_f32_16x16x32_bf16(af[i], bfr[j], acc[i][j], 0, 0, 0);
        }
        __syncthreads();
    }

    int rb = (lane >> 4) * 4;
    int cb = lane & 15;
#pragma unroll
    for (int i = 0; i < 4; ++i) {
#pragma unroll
        for (int j = 0; j < 4; ++j) {
            int gn = n0 + wn * 64 + j * 16 + cb;
#pragma unroll
            for (int rg = 0; rg < 4; ++rg) {
                int gm = m0 + wm * 64 + i * 16 + rb + rg;
                if (gm >= mguard) continue;
                float v = acc[i][j][rg];
                if (mode == 0) {
                    Cf[(size_t)gm * N + gn] = v;
                } else if (mode == 1) {
                    v += bias[gn];
                    v = 0.5f * v * (1.f + erff(v * 0.70710678118654752f));
                    Cb[(size_t)gm * N + gn] = f2bf(v);
                } else {
                    int tr = m_base + gm;
                    int nrow = tr + 2 * (tr >> 10) + 1;
                    v += bias[gn] + bf2f(res[(size_t)nrow * HIDN + gn]);
                    Cb[(size_t)gm * N + gn] = f2bf(v);
                }
            }
        }
    }
}

// ---------------------------------------------------------------- sq/sk per node row (P fp32, a fp32)
__global__ __launch_bounds__(256) void k_sqsk(
    const float* __restrict__ P, const float* __restrict__ a,
    float* __restrict__ sq, float* __restrict__ sk)
{
    int wave = threadIdx.x >> 6, lane = threadIdx.x & 63;
    int row = blockIdx.x * 4 + wave;
    if (row >= MROWS) return;
    int hh = lane >> 4;
    int o0 = lane * 8;
    int dl = o0 & 127;
    const float* p = P + (size_t)row * HIDN + o0;
    const float* a1 = a + hh * 256 + dl;
    const float* a2 = a1 + 128;
    float s1 = 0.f, s2 = 0.f;
#pragma unroll
    for (int d = 0; d < 8; ++d) {
        float pv = p[d];
        s1 += pv * a1[d];
        s2 += pv * a2[d];
    }
#pragma unroll
    for (int off = 8; off; off >>= 1) {
        s1 += __shfl_xor(s1, off);
        s2 += __shfl_xor(s2, off);
    }
    if ((lane & 15) == 0) {
        sq[row * 4 + hh] = s1;
        sk[row * 4 + hh] = s2;
    }
}

// ---------------------------------------------------------------- token attention + elu + residual + LN (1 wave / token)
__global__ __launch_bounds__(64) void k_attn_token(
    const float* __restrict__ P, const float* __restrict__ sq, const float* __restrict__ sk,
    const float* __restrict__ am, const int* __restrict__ last,
    const float* __restrict__ gam, const float* __restrict__ bet,
    ushort* __restrict__ nb)
{
    int tokid = blockIdx.x;
    int b = tokid >> 10, i = tokid & 1023;
    int lane = threadIdx.x;
    int hh = lane >> 4;
    int base = b * NNODE;
    int qrow = base + 1 + i;

    // fixed 13-slot key list (slot0: global node, 1..11: window, 12: local node)
    int kr[13];
    int val[13];
    int rowok = am[b * SEQ + i] > 0.f ? 1 : 0;
    kr[0] = base; val[0] = rowok;
#pragma unroll
    for (int s = 0; s < 11; ++s) {
        int t = i - 5 + s;
        int inb = (t >= 0) && (t <= SEQ - 1);
        int tt = inb ? t : 0;
        int v = inb && rowok && (am[b * SEQ + tt] > 0.f);
        kr[1 + s] = base + 1 + tt;
        val[1 + s] = v;
    }
    kr[12] = base + SEQ + 1;
    val[12] = (rowok && (i >= last[b])) ? 1 : 0;

    float sqv = sq[qrow * 4 + hh];
    float sc[13];
    float mx = -1e30f;
#pragma unroll
    for (int t = 0; t < 13; ++t) {
        float s = 0.f;
        if (val[t]) {
            s = sqv + sk[kr[t] * 4 + hh];
            s = s >= 0.f ? s : 0.2f * s;
            mx = fmaxf(mx, s);
        }
        sc[t] = s;
    }
    float den = 0.f;
#pragma unroll
    for (int t = 0; t < 13; ++t) {
        float ev = 0.f;
        if (val[t]) ev = expf(sc[t] - mx);
        sc[t] = ev; den += ev;
    }
    float inv = (den > 1e-30f && den < 1e30f) ? 1.f / den : 0.f;

    int o0 = lane * 8;
    float accv[8] = {0.f, 0.f, 0.f, 0.f, 0.f, 0.f, 0.f, 0.f};
#pragma unroll
    for (int t = 0; t < 13; ++t) {
        if (val[t]) {
            float wgt = sc[t] * inv;
            const float* pv = P + (size_t)kr[t] * HIDN + o0;
#pragma unroll
            for (int d = 0; d < 8; ++d) accv[d] += wgt * pv[d];
        }
    }

    ushort* nrow = nb + (size_t)qrow * HIDN + o0;
    float x[8], s1 = 0.f, s2 = 0.f;
#pragma unroll
    for (int d = 0; d < 8; ++d) {
        float v = accv[d];
        v = v > 0.f ? v : expf(v) - 1.f;   // elu
        v += bf2f(nrow[d]);                // residual (read-before-write, same thread)
        x[d] = v; s1 += v; s2 += v * v;
    }
#pragma unroll
    for (int off = 32; off; off >>= 1) { s1 += __shfl_xor(s1, off); s2 += __shfl_xor(s2, off); }
    float mean = s1 * (1.f / 512.f);
    float var = s2 * (1.f / 512.f) - mean * mean; var = fmaxf(var, 0.f);
    float rn = rsqrtf(var + 1e-5f);
#pragma unroll
    for (int d = 0; d < 8; ++d) {
        float y = (x[d] - mean) * rn * gam[o0 + d] + bet[o0 + d];
        nrow[d] = f2bf(y);
    }
}

// ---------------------------------------------------------------- g/l attention, split version
// rw in [0,32): b = rw>>1, isl = rw&1

// stage A: softmax weights e[rw][1026][4] + inverse denominators einv[rw][4]
__global__ __launch_bounds__(256) void k_glsm(
    const float* __restrict__ sq, const float* __restrict__ sk,
    const int* __restrict__ last,
    float* __restrict__ ebuf, float* __restrict__ einv)
{
    __shared__ float red[1024];
    int rw = blockIdx.x, b = rw >> 1, isl = rw & 1;
    int base = b * NNODE;
    int qrow = base + (isl ? (SEQ + 1) : 0);
    int lastb = last[b];
    int tid = threadIdx.x;

    float sqh[4];
#pragma unroll
    for (int h = 0; h < 4; ++h) sqh[h] = sq[qrow * 4 + h];

    float mx[4] = {-1e30f, -1e30f, -1e30f, -1e30f};
    for (int j = tid; j < NNODE; j += 256) {
        bool ok = !isl || (j == 0 || j == SEQ + 1 || (j >= lastb + 1 && j <= SEQ));
        if (ok) {
#pragma unroll
            for (int h = 0; h < 4; ++h) {
                float s = sqh[h] + sk[(base + j) * 4 + h];
                s = s >= 0.f ? s : 0.2f * s;
                mx[h] = fmaxf(mx[h], s);
            }
        }
    }
#pragma unroll
    for (int h = 0; h < 4; ++h) red[tid * 4 + h] = mx[h];
    __syncthreads();
    for (int s = 128; s; s >>= 1) {
        if (tid < s) {
#pragma unroll
            for (int h = 0; h < 4; ++h)
                red[tid * 4 + h] = fmaxf(red[tid * 4 + h], red[(tid + s) * 4 + h]);
        }
        __syncthreads();
    }
#pragma unroll
    for (int h = 0; h < 4; ++h) mx[h] = red[h];
    __syncthreads();

    float sm[4] = {0.f, 0.f, 0.f, 0.f};
    for (int j = tid; j < NNODE; j += 256) {
        bool ok = !isl || (j == 0 || j == SEQ + 1 || (j >= lastb + 1 && j <= SEQ));
#pragma unroll
        for (int h = 0; h < 4; ++h) {
            float v = 0.f;
            if (ok) {
                float s = sqh[h] + sk[(base + j) * 4 + h];
                s = s >= 0.f ? s : 0.2f * s;
                v = expf(s - mx[h]);
            }
            ebuf[((size_t)rw * NNODE + j) * 4 + h] = v;
            sm[h] += v;
        }
    }
#pragma unroll
    for (int h = 0; h < 4; ++h) red[tid * 4 + h] = sm[h];
    __syncthreads();
    for (int s = 128; s; s >>= 1) {
        if (tid < s) {
#pragma unroll
            for (int h = 0; h < 4; ++h) red[tid * 4 + h] += red[(tid + s) * 4 + h];
        }
        __syncthreads();
    }
    if (tid < 4) {
        float den = red[tid];
        einv[rw * 4 + tid] = (den > 1e-30f && den < 1e30f) ? 1.f / den : 0.f;
    }
}

// stage B: PV partials over j-chunks. grid (9, 32)
__global__ __launch_bounds__(256) void k_glpv(
    const float* __restrict__ P, const float* __restrict__ ebuf,
    float* __restrict__ pout2)
{
    __shared__ float es[JCH * 4];
    int p = blockIdx.x, rw = blockIdx.y;
    int b = rw >> 1;
    int base = b * NNODE;
    int tid = threadIdx.x;
    for (int t = tid; t < JCH * 4; t += 256)
        es[t] = ebuf[((size_t)rw * NNODE + p * JCH) * 4 + t];
    __syncthreads();
    int o0 = tid, o1 = tid + 256;
    int h0 = o0 >> 7, h1 = o1 >> 7;
    const float* Pb = P + (size_t)(base + p * JCH) * HIDN;
    float a0 = 0.f, a1 = 0.f;
    for (int j = 0; j < JCH; ++j) {
        const float* pr = Pb + (size_t)j * HIDN;
        a0 += es[j * 4 + h0] * pr[o0];
        a1 += es[j * 4 + h1] * pr[o1];
    }
    float* o = pout2 + ((size_t)rw * 9 + p) * HIDN;
    o[o0] = a0;
    o[o1] = a1;
}

// stage C: reduce partials + elu + residual + LN -> nb
__global__ __launch_bounds__(256) void k_glred(
    const float* __restrict__ pout2, const float* __restrict__ einv,
    const float* __restrict__ gam, const float* __restrict__ bet,
    ushort* __restrict__ nb)
{
    __shared__ float red[512];
    int rw = blockIdx.x, b = rw >> 1, isl = rw & 1;
    size_t qrow = (size_t)b * NNODE + (isl ? SEQ + 1 : 0);
    int tid = threadIdx.x;
    float xv[2], s1 = 0.f, s2 = 0.f;
#pragma unroll
    for (int u = 0; u < 2; ++u) {
        int o = tid + u * 256;
        int h = o >> 7;
        float acc = 0.f;
#pragma unroll
        for (int p = 0; p < 9; ++p)
            acc += pout2[((size_t)rw * 9 + p) * HIDN + o];
        acc *= einv[rw * 4 + h];
        float v = acc > 0.f ? acc : expf(acc) - 1.f;
        v += bf2f(nb[qrow * HIDN + o]);
        xv[u] = v; s1 += v; s2 += v * v;
    }
    red[tid] = s1;
    __syncthreads();
    for (int s = 128; s; s >>= 1) { if (tid < s) red[tid] += red[tid + s]; __syncthreads(); }
    float mean = red[0] * (1.f / 512.f);
    __syncthreads();
    red[tid] = s2;
    __syncthreads();
    for (int s = 128; s; s >>= 1) { if (tid < s) red[tid] += red[tid + s]; __syncthreads(); }
    float var = red[0] * (1.f / 512.f) - mean * mean; var = fmaxf(var, 0.f);
    float rn = rsqrtf(var + 1e-5f);
#pragma unroll
    for (int u = 0; u < 2; ++u) {
        int o = tid + u * 256;
        float y = (xv[u] - mean) * rn * gam[o] + bet[o];
        nb[qrow * HIDN + o] = f2bf(y);
    }
}

// ---------------------------------------------------------------- g/l FFN, parallel split version
// scratch (in Hmid region): pmid[32][8][2048] f32, mid[32][2048] f32, pout[32][8][512] f32

// stage 1: FFN1 partials over k-split p (i in [64p, 64p+64))
__global__ __launch_bounds__(256) void k_fgl1(
    const ushort* __restrict__ nb, const float* __restrict__ w1,
    float* __restrict__ pmid)
{
    __shared__ float xs[64];
    int p = blockIdx.x, rw = blockIdx.y;
    int b = rw >> 1, isl = rw & 1;
    int idx = isl ? 2 : 0;
    size_t nrow = (size_t)b * NNODE + (isl ? SEQ + 1 : 0);
    int tid = threadIdx.x;
    if (tid < 64) xs[tid] = bf2f(nb[nrow * HIDN + p * 64 + tid]);
    __syncthreads();
    const float* W1 = w1 + (size_t)idx * HIDN * FFD + (size_t)p * 64 * FFD;
    float acc[8] = {0.f, 0.f, 0.f, 0.f, 0.f, 0.f, 0.f, 0.f};
    for (int ii = 0; ii < 64; ++ii) {
        float xv = xs[ii];
        const float* wrow = W1 + (size_t)ii * FFD + tid;
#pragma unroll
        for (int u = 0; u < 8; ++u) acc[u] += xv * wrow[u * 256];
    }
    float* o = pmid + ((size_t)rw * 8 + p) * FFD + tid;
#pragma unroll
    for (int u = 0; u < 8; ++u) o[u * 256] = acc[u];
}

// stage 2: reduce partials + bias + gelu -> mid
__global__ __launch_bounds__(256) void k_fgl2(
    const float* __restrict__ pmid, const float* __restrict__ b1,
    float* __restrict__ mid)
{
    int g = blockIdx.x * 256 + threadIdx.x;   // 16384 threads, 4 elems each
    int e4 = g * 4;
    int rw = e4 >> 11;
    int m = e4 & 2047;
    int isl = rw & 1;
    int idx = isl ? 2 : 0;
#pragma unroll
    for (int d = 0; d < 4; ++d) {
        float s = 0.f;
#pragma unroll
        for (int p = 0; p < 8; ++p)
            s += pmid[((size_t)rw * 8 + p) * FFD + m + d];
        s += b1[idx * FFD + m + d];
        mid[(size_t)rw * FFD + m + d] = 0.5f * s * (1.f + erff(s * 0.70710678118654752f));
    }
}

// stage 3: FFN2 partials over m-split p (m in [256p, 256p+256))
__global__ __launch_bounds__(256) void k_fgl3(
    const float* __restrict__ mid, const float* __restrict__ w2,
    float* __restrict__ pout)
{
    __shared__ float ms[256];
    int p = blockIdx.x, rw = blockIdx.y;
    int isl = rw & 1;
    int idx = isl ? 2 : 0;
    int tid = threadIdx.x;
    ms[tid] = mid[(size_t)rw * FFD + p * 256 + tid];
    __syncthreads();
    const float* W2 = w2 + (size_t)idx * FFD * HIDN + (size_t)p * 256 * HIDN;
    float a0 = 0.f, a1 = 0.f;
    for (int mm = 0; mm < 256; ++mm) {
        float mv = ms[mm];
        const float* wrow = W2 + (size_t)mm * HIDN + tid;
        a0 += mv * wrow[0];
        a1 += mv * wrow[256];
    }
    float* o = pout + ((size_t)rw * 8 + p) * HIDN + tid;
    o[0] = a0;
    o[256] = a1;
}

// stage 4: reduce + bias + residual + out-LN + store
__global__ __launch_bounds__(256) void k_fgl4(
    const float* __restrict__ pout, const float* __restrict__ b2,
    const ushort* __restrict__ nb,
    const float* __restrict__ og, const float* __restrict__ obt,
    float* __restrict__ out)
{
    __shared__ float red[512];
    int rw = blockIdx.x;
    int b = rw >> 1, isl = rw & 1;
    int idx = isl ? 2 : 0;
    size_t nrow = (size_t)b * NNODE + (isl ? SEQ + 1 : 0);
    int tid = threadIdx.x;
    float xv[2], s1 = 0.f, s2 = 0.f;
#pragma unroll
    for (int u = 0; u < 2; ++u) {
        int o = tid + u * 256;
        float s = 0.f;
#pragma unroll
        for (int p = 0; p < 8; ++p)
            s += pout[((size_t)rw * 8 + p) * HIDN + o];
        s += b2[idx * HIDN + o] + bf2f(nb[nrow * HIDN + o]);
        xv[u] = s; s1 += s; s2 += s * s;
    }
    red[tid] = s1;
    __syncthreads();
    for (int s = 128; s; s >>= 1) { if (tid < s) red[tid] += red[tid + s]; __syncthreads(); }
    float mean = red[0] * (1.f / 512.f);
    __syncthreads();
    red[tid] = s2;
    __syncthreads();
    for (int s = 128; s; s >>= 1) { if (tid < s) red[tid] += red[tid + s]; __syncthreads(); }
    float var = red[0] * (1.f / 512.f) - mean * mean; var = fmaxf(var, 0.f);
    float rn = rsqrtf(var + 1e-5f);
    size_t obase = isl ? ((size_t)8192 + (size_t)MTOK * HIDN + (size_t)b * HIDN)
                       : ((size_t)b * HIDN);
#pragma unroll
    for (int u = 0; u < 2; ++u) {
        int o = tid + u * 256;
        out[obase + o] = (xv[u] - mean) * rn * og[idx * HIDN + o] + obt[idx * HIDN + o];
    }
}

// ---------------------------------------------------------------- rowwise LN: bf16 in -> fp32 out (tokens)
__global__ __launch_bounds__(64) void k_ln_rows(
    const ushort* __restrict__ X, const float* __restrict__ gam,
    const float* __restrict__ bet, float* __restrict__ out)
{
    int row = blockIdx.x, lane = threadIdx.x;
    const ushort* x = X + (size_t)row * HIDN + lane * 8;
    float v[8], s1 = 0.f, s2 = 0.f;
#pragma unroll
    for (int d = 0; d < 8; ++d) { v[d] = bf2f(x[d]); s1 += v[d]; s2 += v[d] * v[d]; }
#pragma unroll
    for (int off = 32; off; off >>= 1) { s1 += __shfl_xor(s1, off); s2 += __shfl_xor(s2, off); }
    float mean = s1 * (1.f / 512.f);
    float var = s2 * (1.f / 512.f) - mean * mean; var = fmaxf(var, 0.f);
    float rn = rsqrtf(var + 1e-5f);
    int o0 = lane * 8;
    float* o = out + (size_t)row * HIDN + o0;
#pragma unroll
    for (int d = 0; d < 8; ++d)
        o[d] = (v[d] - mean) * rn * gam[o0 + d] + bet[o0 + d];
}

// ================================================================ launch
extern "C" void kernel_launch(void* const* d_in, const int* in_sizes, int n_in,
                              void* d_out, int out_size, void* d_ws, size_t ws_size,
                              hipStream_t stream)
{
    (void)in_sizes; (void)n_in; (void)out_size; (void)ws_size;
    const float* g_emb   = (const float*)d_in[0];
    const float* tok_emb = (const float*)d_in[1];
    const float* l_emb   = (const float*)d_in[2];
    const float* am      = (const float*)d_in[3];
    const int*   last    = (const int*)d_in[4];
    const float* gat_W   = (const float*)d_in[5];
    const float* gat_a   = (const float*)d_in[6];
    const float* ln_g    = (const float*)d_in[7];
    const float* ln_b    = (const float*)d_in[8];
    const float* ffn_w1  = (const float*)d_in[9];
    const float* ffn_b1  = (const float*)d_in[10];
    const float* ffn_w2  = (const float*)d_in[11];
    const float* ffn_b2  = (const float*)d_in[12];
    const float* oln_g   = (const float*)d_in[13];
    const float* oln_b   = (const float*)d_in[14];
    float* out = (float*)d_out;

    // workspace layout — ~33.1 MiB (proven). every region fully written before read.
    char* w = (char*)d_ws;
    ushort* nodes_b = (ushort*)w; w += (size_t)MPAD * HIDN * 2;   // 16.9 MB  bf16 node state
    ushort* Hmid    = (ushort*)w; w += (size_t)FCH * FFD * 2;     //  8.4 MB
    ushort* Obuf    = (ushort*)w; w += (size_t)FCH * HIDN * 2;    //  2.1 MB
    ushort* w1t     = (ushort*)w; w += (size_t)FFD * HIDN * 2;    //  2.1 MB
    ushort* w2t     = (ushort*)w; w += (size_t)FFD * HIDN * 2;    //  2.1 MB
    ushort* gatWb   = (ushort*)w; w += (size_t)2 * HIDN * HIDN * 2; // 1.0 MB
    float*  sqb     = (float*)w;  w += (size_t)MPAD * 4 * 4;      //  0.26 MB
    float*  skb     = (float*)w;  w += (size_t)MPAD * 4 * 4;      //  0.26 MB

    // g/l FFN scratch in Hmid[0 .. 2.75 MB) — used after the layer loop,
    // before the token FFN chunks overwrite Hmid.
    float* pmid = (float*)Hmid;                       // 32*8*2048 f32 = 2 MB
    float* mid  = pmid + (size_t)32 * 8 * FFD;        // 32*2048 f32 = 256 KB
    float* pout = mid + (size_t)32 * FFD;             // 32*8*512 f32 = 512 KB

    // g/l attention scratch in Hmid[3 MB .. 4.2 MB) — used inside the layer loop.
    float* ebuf  = (float*)((char*)Hmid + (size_t)3 * 1024 * 1024); // 32*1026*4 f32 = 513 KB
    float* einv  = ebuf + (size_t)32 * NNODE * 4;                    // 128 f32
    float* pout2 = einv + 128;                                       // 32*9*512 f32 = 576 KB

    // P (node projections, MROWS x 512 fp32) aliases d_out: exactly out_size
    // floats, dead before the first output write.
    float* P = out;

    k_build_nodes<<<MPAD * HIDN / 256, 256, 0, stream>>>(g_emb, tok_emb, l_emb, nodes_b);
    k_cvt<<<(2 * HIDN * HIDN) / 256, 256, 0, stream>>>(gat_W, gatWb, 2 * HIDN * HIDN);
    // w1[1] (512x2048) -> w1t (2048x512); w2[1] (2048x512) -> w2t (512x2048)
    k_transpose<<<dim3(FFD / 32, HIDN / 32), dim3(32, 8), 0, stream>>>(ffn_w1 + (size_t)HIDN * FFD, w1t, HIDN, FFD);
    k_transpose<<<dim3(HIDN / 32, FFD / 32), dim3(32, 8), 0, stream>>>(ffn_w2 + (size_t)FFD * HIDN, w2t, FFD, HIDN);

    for (int k = 0; k < 2; ++k) {
        k_gemm_bt<<<dim3(HIDN / BN, MPAD / BM), 256, 0, stream>>>(
            nodes_b, gatWb + (size_t)k * HIDN * HIDN, P, nullptr, nullptr, nullptr,
            HIDN, HIDN, 0, 0, 0, MROWS);
        k_sqsk<<<MROWS / 4, 256, 0, stream>>>(P, gat_a + k * NHEAD * 2 * DHEAD, sqb, skb);
        k_attn_token<<<MTOK, 64, 0, stream>>>(P, sqb, skb, am, last,
                                              ln_g + k * HIDN, ln_b + k * HIDN, nodes_b);
        k_glsm<<<32, 256, 0, stream>>>(sqb, skb, last, ebuf, einv);
        k_glpv<<<dim3(9, 32), 256, 0, stream>>>(P, ebuf, pout2);
        k_glred<<<32, 256, 0, stream>>>(pout2, einv, ln_g + k * HIDN, ln_b + k * HIDN, nodes_b);
    }

    // g/l FFN (parallel split), scratch in Hmid — must precede token FFN chunks.
    k_fgl1<<<dim3(8, 32), 256, 0, stream>>>(nodes_b, ffn_w1, pmid);
    k_fgl2<<<64, 256, 0, stream>>>(pmid, ffn_b1, mid);
    k_fgl3<<<dim3(8, 32), 256, 0, stream>>>(mid, ffn_w2, pout);
    k_fgl4<<<32, 256, 0, stream>>>(pout, ffn_b2, nodes_b, oln_g, oln_b, out);

    // P (= d_out) dead from here (token outputs only).
    for (int c = 0; c < MTOK / FCH; ++c) {
        int mb = c * FCH;
        k_gemm_bt<<<dim3(FFD / BN, FCH / BM), 256, 0, stream>>>(
            nodes_b, w1t, nullptr, Hmid, ffn_b1 + FFD, nullptr, FFD, HIDN, 1, 1, mb, FCH);
        k_gemm_bt<<<dim3(HIDN / BN, FCH / BM), 256, 0, stream>>>(
            Hmid, w2t, nullptr, Obuf, ffn_b2 + HIDN, nodes_b, HIDN, FFD, 2, 0, mb, FCH);
        k_ln_rows<<<FCH, 64, 0, stream>>>(Obuf, oln_g + HIDN, oln_b + HIDN,
                                          out + 8192 + (size_t)mb * HIDN);
    }
}

// Round 7
// 872.320 us; speedup vs baseline: 1.7840x; 1.3243x over previous
//
#include <hip/hip_runtime.h>
#include <stdint.h>
#include <math.h>

#define HIDN 512
#define NHEAD 4
#define DHEAD 128
#define BATCH 16
#define SEQ 1024
#define NNODE 1026
#define MROWS (BATCH * NNODE)   // 16416
#define MPAD 16512              // 129 * 128
#define MTOK (BATCH * SEQ)      // 16384
#define FFD 2048
#define NCH 256                 // FFN mid-col chunk (8 chunks)
#define JCH 114                 // gl-attn j-chunk (9 * 114 = 1026)

typedef short bf16x8 __attribute__((ext_vector_type(8)));
typedef float f32x4 __attribute__((ext_vector_type(4)));

__device__ __forceinline__ float bf2f(ushort u) {
    union { uint32_t i; float f; } v; v.i = ((uint32_t)u) << 16; return v.f;
}
__device__ __forceinline__ ushort f2bf(float f) {
    uint32_t x = __float_as_uint(f);
    return (ushort)((x + 0x7fffu + ((x >> 16) & 1u)) >> 16);
}
__device__ __forceinline__ float gelu(float v) {
    return 0.5f * v * (1.f + erff(v * 0.70710678118654752f));
}
// swizzled index into 64x128 f32 epilogue tile (float4-granular XOR)
__device__ __forceinline__ int cswz(int row, int col) {
    return row * 128 + ((((col >> 2) ^ (row & 7)) & 31) << 2) + (col & 3);
}

// ---------------------------------------------------------------- build nodes: fp32 in -> bf16 node buffer
__global__ __launch_bounds__(256) void k_build_nodes(
    const float* __restrict__ g, const float* __restrict__ tok,
    const float* __restrict__ l, ushort* __restrict__ nb)
{
    int idx = blockIdx.x * 256 + threadIdx.x;       // MPAD*HIDN total
    int r = idx >> 9, c = idx & 511;
    float u = 0.f;
    if (r < MROWS) {
        int b = r / NNODE;
        int n = r - b * NNODE;
        if (n == 0)            u = g[b * HIDN + c];
        else if (n <= SEQ)     u = tok[((size_t)b * SEQ + (n - 1)) * HIDN + c];
        else                   u = l[b * HIDN + c];
    }
    nb[idx] = f2bf(u);
}

// ---------------------------------------------------------------- fp32 -> bf16 flat convert
__global__ __launch_bounds__(256) void k_cvt(
    const float* __restrict__ in, ushort* __restrict__ out, int n)
{
    int idx = blockIdx.x * 256 + threadIdx.x;
    if (idx < n) out[idx] = f2bf(in[idx]);
}

// ---------------------------------------------------------------- transpose fp32 -> bf16
__global__ __launch_bounds__(256) void k_transpose(
    const float* __restrict__ in, ushort* __restrict__ out, int R, int C)
{
    __shared__ float t[32][33];
    int x = blockIdx.x * 32 + threadIdx.x;
    int y0 = blockIdx.y * 32;
    for (int dy = threadIdx.y; dy < 32; dy += 8)
        t[dy][threadIdx.x] = in[(size_t)(y0 + dy) * C + x];
    __syncthreads();
    int ox = y0 + threadIdx.x;
    int oy0 = blockIdx.x * 32;
    for (int dy = threadIdx.y; dy < 32; dy += 8)
        out[(size_t)(oy0 + dy) * R + ox] = f2bf(t[threadIdx.x][dy]);
}

// ---------------------------------------------------------------- MFMA GEMM (A: rowmaj MxK bf16 lda=K, Bt: NxK rowmaj bf16, ldb free)
// mode 1: Cb bf16 = gelu(A*B + bias)
// else  : Cf fp32 = A*B  (first=1) or Cf += A*B (first=0)
// amap: A row gm remapped token->node row
#define BM 128
#define BN 128
#define BK 64

__global__ __launch_bounds__(256) void k_gemm_bt(
    const ushort* __restrict__ A, const ushort* __restrict__ Bt,
    float* __restrict__ Cf, ushort* __restrict__ Cb,
    const float* __restrict__ bias,
    int N, int K, int ldb, int mode, int amap, int mguard, int first)
{
    __shared__ ushort smem[BM * BK + BN * BK];   // 32 KB
    ushort* sA = smem;
    ushort* sB = smem + BM * BK;
    int tid = threadIdx.x;
    int lane = tid & 63;
    int wave = tid >> 6;
    int wm = wave >> 1, wn = wave & 1;
    int m0 = blockIdx.y * BM;
    int n0 = blockIdx.x * BN;

    f32x4 acc[4][4];
#pragma unroll
    for (int i = 0; i < 4; ++i)
#pragma unroll
        for (int j = 0; j < 4; ++j) acc[i][j] = (f32x4){0.f, 0.f, 0.f, 0.f};

    int lr = lane >> 3;              // row within 8-row chunk
    int gco = ((lane & 7) ^ lr) * 8; // XOR-swizzled col-chunk offset (elements)

    for (int k0 = 0; k0 < K; k0 += BK) {
#pragma unroll
        for (int t = 0; t < 4; ++t) {
            int q = wave * 4 + t;            // 0..15 : 8-row chunk id
            int rr8 = q * 8 + lr;
            int grA = m0 + rr8;
            if (amap) grA = grA + 2 * (grA >> 10) + 1;
            const ushort* gpA = A + (size_t)grA * K + (k0 + gco);
            __builtin_amdgcn_global_load_lds(
                (const __attribute__((address_space(1))) void*)gpA,
                (__attribute__((address_space(3))) void*)&sA[q * 512], 16, 0, 0);
            int grB = n0 + rr8;
            const ushort* gpB = Bt + (size_t)grB * ldb + (k0 + gco);
            __builtin_amdgcn_global_load_lds(
                (const __attribute__((address_space(1))) void*)gpB,
                (__attribute__((address_space(3))) void*)&sB[q * 512], 16, 0, 0);
        }
        __syncthreads();
        int rr = lane & 7;
        int rhi = (lane & 15) >> 3;
#pragma unroll
        for (int kk = 0; kk < BK; kk += 32) {
            int c4 = (kk >> 3) + (lane >> 4);          // col-chunk 0..7
            int swz = rr * 64 + ((c4 ^ rr) << 3);
            bf16x8 af[4], bfr[4];
#pragma unroll
            for (int i = 0; i < 4; ++i)
                af[i] = *reinterpret_cast<const bf16x8*>(&sA[(wm * 8 + i * 2 + rhi) * 512 + swz]);
#pragma unroll
            for (int j = 0; j < 4; ++j)
                bfr[j] = *reinterpret_cast<const bf16x8*>(&sB[(wn * 8 + j * 2 + rhi) * 512 + swz]);
#pragma unroll
            for (int i = 0; i < 4; ++i)
#pragma unroll
                for (int j = 0; j < 4; ++j)
                    acc[i][j] = __builtin_amdgcn_mfma_f32_16x16x32_bf16(af[i], bfr[j], acc[i][j], 0, 0, 0);
        }
        __syncthreads();
    }

    // -------- coalesced epilogue: 2 passes of 64 rows via LDS f32 tile
    float* sC = (float*)smem;        // 64 x 128 f32 = 32 KB
    int rb = (lane >> 4) * 4;
    int cb = lane & 15;
    int lrow = tid >> 2;             // 0..63
    int lcol = (tid & 3) << 5;       // 0,32,64,96
#pragma unroll
    for (int pass = 0; pass < 2; ++pass) {
        if (wm == pass) {
#pragma unroll
            for (int i = 0; i < 4; ++i)
#pragma unroll
                for (int j = 0; j < 4; ++j)
#pragma unroll
                    for (int rg = 0; rg < 4; ++rg)
                        sC[cswz(i * 16 + rb + rg, wn * 64 + j * 16 + cb)] = acc[i][j][rg];
        }
        __syncthreads();
        int gm = m0 + pass * 64 + lrow;
        if (gm < mguard) {
            int gn0 = n0 + lcol;
            float v[32];
#pragma unroll
            for (int e4 = 0; e4 < 8; ++e4) {
                float4 t = *(const float4*)&sC[cswz(lrow, lcol + e4 * 4)];
                v[e4 * 4 + 0] = t.x; v[e4 * 4 + 1] = t.y;
                v[e4 * 4 + 2] = t.z; v[e4 * 4 + 3] = t.w;
            }
            if (mode == 1) {
                uint4* dst = (uint4*)(Cb + (size_t)gm * N + gn0);
#pragma unroll
                for (int q2 = 0; q2 < 4; ++q2) {
                    float s[8];
#pragma unroll
                    for (int t = 0; t < 8; ++t)
                        s[t] = gelu(v[q2 * 8 + t] + bias[gn0 + q2 * 8 + t]);
                    uint4 w;
                    w.x = (uint32_t)f2bf(s[0]) | ((uint32_t)f2bf(s[1]) << 16);
                    w.y = (uint32_t)f2bf(s[2]) | ((uint32_t)f2bf(s[3]) << 16);
                    w.z = (uint32_t)f2bf(s[4]) | ((uint32_t)f2bf(s[5]) << 16);
                    w.w = (uint32_t)f2bf(s[6]) | ((uint32_t)f2bf(s[7]) << 16);
                    dst[q2] = w;
                }
            } else {
                float4* dst = (float4*)(Cf + (size_t)gm * N + gn0);
#pragma unroll
                for (int e4 = 0; e4 < 8; ++e4) {
                    float4 t;
                    t.x = v[e4 * 4 + 0]; t.y = v[e4 * 4 + 1];
                    t.z = v[e4 * 4 + 2]; t.w = v[e4 * 4 + 3];
                    if (!first) {
                        float4 o = dst[e4];
                        t.x += o.x; t.y += o.y; t.z += o.z; t.w += o.w;
                    }
                    dst[e4] = t;
                }
            }
        }
        __syncthreads();
    }
}

// ---------------------------------------------------------------- sq/sk per node row (P fp32, a fp32)
__global__ __launch_bounds__(256) void k_sqsk(
    const float* __restrict__ P, const float* __restrict__ a,
    float* __restrict__ sq, float* __restrict__ sk)
{
    int wave = threadIdx.x >> 6, lane = threadIdx.x & 63;
    int row = blockIdx.x * 4 + wave;
    if (row >= MROWS) return;
    int hh = lane >> 4;
    int o0 = lane * 8;
    int dl = o0 & 127;
    const float* p = P + (size_t)row * HIDN + o0;
    const float* a1 = a + hh * 256 + dl;
    const float* a2 = a1 + 128;
    float s1 = 0.f, s2 = 0.f;
#pragma unroll
    for (int d = 0; d < 8; ++d) {
        float pv = p[d];
        s1 += pv * a1[d];
        s2 += pv * a2[d];
    }
#pragma unroll
    for (int off = 8; off; off >>= 1) {
        s1 += __shfl_xor(s1, off);
        s2 += __shfl_xor(s2, off);
    }
    if ((lane & 15) == 0) {
        sq[row * 4 + hh] = s1;
        sk[row * 4 + hh] = s2;
    }
}

// ---------------------------------------------------------------- token attention + elu + residual + LN (1 wave / token)
__global__ __launch_bounds__(64) void k_attn_token(
    const float* __restrict__ P, const float* __restrict__ sq, const float* __restrict__ sk,
    const float* __restrict__ am, const int* __restrict__ last,
    const float* __restrict__ gam, const float* __restrict__ bet,
    ushort* __restrict__ nb)
{
    int tokid = blockIdx.x;
    int b = tokid >> 10, i = tokid & 1023;
    int lane = threadIdx.x;
    int hh = lane >> 4;
    int base = b * NNODE;
    int qrow = base + 1 + i;

    int kr[13];
    int val[13];
    int rowok = am[b * SEQ + i] > 0.f ? 1 : 0;
    kr[0] = base; val[0] = rowok;
#pragma unroll
    for (int s = 0; s < 11; ++s) {
        int t = i - 5 + s;
        int inb = (t >= 0) && (t <= SEQ - 1);
        int tt = inb ? t : 0;
        int v = inb && rowok && (am[b * SEQ + tt] > 0.f);
        kr[1 + s] = base + 1 + tt;
        val[1 + s] = v;
    }
    kr[12] = base + SEQ + 1;
    val[12] = (rowok && (i >= last[b])) ? 1 : 0;

    float sqv = sq[qrow * 4 + hh];
    float sc[13];
    float mx = -1e30f;
#pragma unroll
    for (int t = 0; t < 13; ++t) {
        float s = 0.f;
        if (val[t]) {
            s = sqv + sk[kr[t] * 4 + hh];
            s = s >= 0.f ? s : 0.2f * s;
            mx = fmaxf(mx, s);
        }
        sc[t] = s;
    }
    float den = 0.f;
#pragma unroll
    for (int t = 0; t < 13; ++t) {
        float ev = 0.f;
        if (val[t]) ev = expf(sc[t] - mx);
        sc[t] = ev; den += ev;
    }
    float inv = (den > 1e-30f && den < 1e30f) ? 1.f / den : 0.f;

    int o0 = lane * 8;
    float accv[8] = {0.f, 0.f, 0.f, 0.f, 0.f, 0.f, 0.f, 0.f};
#pragma unroll
    for (int t = 0; t < 13; ++t) {
        if (val[t]) {
            float wgt = sc[t] * inv;
            const float* pv = P + (size_t)kr[t] * HIDN + o0;
#pragma unroll
            for (int d = 0; d < 8; ++d) accv[d] += wgt * pv[d];
        }
    }

    ushort* nrow = nb + (size_t)qrow * HIDN + o0;
    float x[8], s1 = 0.f, s2 = 0.f;
#pragma unroll
    for (int d = 0; d < 8; ++d) {
        float v = accv[d];
        v = v > 0.f ? v : expf(v) - 1.f;   // elu
        v += bf2f(nrow[d]);                // residual
        x[d] = v; s1 += v; s2 += v * v;
    }
#pragma unroll
    for (int off = 32; off; off >>= 1) { s1 += __shfl_xor(s1, off); s2 += __shfl_xor(s2, off); }
    float mean = s1 * (1.f / 512.f);
    float var = s2 * (1.f / 512.f) - mean * mean; var = fmaxf(var, 0.f);
    float rn = rsqrtf(var + 1e-5f);
#pragma unroll
    for (int d = 0; d < 8; ++d) {
        float y = (x[d] - mean) * rn * gam[o0 + d] + bet[o0 + d];
        nrow[d] = f2bf(y);
    }
}

// ---------------------------------------------------------------- g/l attention, split version
__global__ __launch_bounds__(256) void k_glsm(
    const float* __restrict__ sq, const float* __restrict__ sk,
    const int* __restrict__ last,
    float* __restrict__ ebuf, float* __restrict__ einv)
{
    __shared__ float red[1024];
    int rw = blockIdx.x, b = rw >> 1, isl = rw & 1;
    int base = b * NNODE;
    int qrow = base + (isl ? (SEQ + 1) : 0);
    int lastb = last[b];
    int tid = threadIdx.x;

    float sqh[4];
#pragma unroll
    for (int h = 0; h < 4; ++h) sqh[h] = sq[qrow * 4 + h];

    float mx[4] = {-1e30f, -1e30f, -1e30f, -1e30f};
    for (int j = tid; j < NNODE; j += 256) {
        bool ok = !isl || (j == 0 || j == SEQ + 1 || (j >= lastb + 1 && j <= SEQ));
        if (ok) {
#pragma unroll
            for (int h = 0; h < 4; ++h) {
                float s = sqh[h] + sk[(base + j) * 4 + h];
                s = s >= 0.f ? s : 0.2f * s;
                mx[h] = fmaxf(mx[h], s);
            }
        }
    }
#pragma unroll
    for (int h = 0; h < 4; ++h) red[tid * 4 + h] = mx[h];
    __syncthreads();
    for (int s = 128; s; s >>= 1) {
        if (tid < s) {
#pragma unroll
            for (int h = 0; h < 4; ++h)
                red[tid * 4 + h] = fmaxf(red[tid * 4 + h], red[(tid + s) * 4 + h]);
        }
        __syncthreads();
    }
#pragma unroll
    for (int h = 0; h < 4; ++h) mx[h] = red[h];
    __syncthreads();

    float sm[4] = {0.f, 0.f, 0.f, 0.f};
    for (int j = tid; j < NNODE; j += 256) {
        bool ok = !isl || (j == 0 || j == SEQ + 1 || (j >= lastb + 1 && j <= SEQ));
#pragma unroll
        for (int h = 0; h < 4; ++h) {
            float v = 0.f;
            if (ok) {
                float s = sqh[h] + sk[(base + j) * 4 + h];
                s = s >= 0.f ? s : 0.2f * s;
                v = expf(s - mx[h]);
            }
            ebuf[((size_t)rw * NNODE + j) * 4 + h] = v;
            sm[h] += v;
        }
    }
#pragma unroll
    for (int h = 0; h < 4; ++h) red[tid * 4 + h] = sm[h];
    __syncthreads();
    for (int s = 128; s; s >>= 1) {
        if (tid < s) {
#pragma unroll
            for (int h = 0; h < 4; ++h) red[tid * 4 + h] += red[(tid + s) * 4 + h];
        }
        __syncthreads();
    }
    if (tid < 4) {
        float den = red[tid];
        einv[rw * 4 + tid] = (den > 1e-30f && den < 1e30f) ? 1.f / den : 0.f;
    }
}

__global__ __launch_bounds__(256) void k_glpv(
    const float* __restrict__ P, const float* __restrict__ ebuf,
    float* __restrict__ pout2)
{
    __shared__ float es[JCH * 4];
    int p = blockIdx.x, rw = blockIdx.y;
    int b = rw >> 1;
    int base = b * NNODE;
    int tid = threadIdx.x;
    for (int t = tid; t < JCH * 4; t += 256)
        es[t] = ebuf[((size_t)rw * NNODE + p * JCH) * 4 + t];
    __syncthreads();
    int o0 = tid, o1 = tid + 256;
    int h0 = o0 >> 7, h1 = o1 >> 7;
    const float* Pb = P + (size_t)(base + p * JCH) * HIDN;
    float a0 = 0.f, a1 = 0.f;
    for (int j = 0; j < JCH; ++j) {
        const float* pr = Pb + (size_t)j * HIDN;
        a0 += es[j * 4 + h0] * pr[o0];
        a1 += es[j * 4 + h1] * pr[o1];
    }
    float* o = pout2 + ((size_t)rw * 9 + p) * HIDN;
    o[o0] = a0;
    o[o1] = a1;
}

__global__ __launch_bounds__(256) void k_glred(
    const float* __restrict__ pout2, const float* __restrict__ einv,
    const float* __restrict__ gam, const float* __restrict__ bet,
    ushort* __restrict__ nb)
{
    __shared__ float red[512];
    int rw = blockIdx.x, b = rw >> 1, isl = rw & 1;
    size_t qrow = (size_t)b * NNODE + (isl ? SEQ + 1 : 0);
    int tid = threadIdx.x;
    float xv[2], s1 = 0.f, s2 = 0.f;
#pragma unroll
    for (int u = 0; u < 2; ++u) {
        int o = tid + u * 256;
        int h = o >> 7;
        float acc = 0.f;
#pragma unroll
        for (int p = 0; p < 9; ++p)
            acc += pout2[((size_t)rw * 9 + p) * HIDN + o];
        acc *= einv[rw * 4 + h];
        float v = acc > 0.f ? acc : expf(acc) - 1.f;
        v += bf2f(nb[qrow * HIDN + o]);
        xv[u] = v; s1 += v; s2 += v * v;
    }
    red[tid] = s1;
    __syncthreads();
    for (int s = 128; s; s >>= 1) { if (tid < s) red[tid] += red[tid + s]; __syncthreads(); }
    float mean = red[0] * (1.f / 512.f);
    __syncthreads();
    red[tid] = s2;
    __syncthreads();
    for (int s = 128; s; s >>= 1) { if (tid < s) red[tid] += red[tid + s]; __syncthreads(); }
    float var = red[0] * (1.f / 512.f) - mean * mean; var = fmaxf(var, 0.f);
    float rn = rsqrtf(var + 1e-5f);
#pragma unroll
    for (int u = 0; u < 2; ++u) {
        int o = tid + u * 256;
        float y = (xv[u] - mean) * rn * gam[o] + bet[o];
        nb[qrow * HIDN + o] = f2bf(y);
    }
}

// ---------------------------------------------------------------- g/l FFN, parallel split version
__global__ __launch_bounds__(256) void k_fgl1(
    const ushort* __restrict__ nb, const float* __restrict__ w1,
    float* __restrict__ pmid)
{
    __shared__ float xs[64];
    int p = blockIdx.x, rw = blockIdx.y;
    int b = rw >> 1, isl = rw & 1;
    int idx = isl ? 2 : 0;
    size_t nrow = (size_t)b * NNODE + (isl ? SEQ + 1 : 0);
    int tid = threadIdx.x;
    if (tid < 64) xs[tid] = bf2f(nb[nrow * HIDN + p * 64 + tid]);
    __syncthreads();
    const float* W1 = w1 + (size_t)idx * HIDN * FFD + (size_t)p * 64 * FFD;
    float acc[8] = {0.f, 0.f, 0.f, 0.f, 0.f, 0.f, 0.f, 0.f};
    for (int ii = 0; ii < 64; ++ii) {
        float xv = xs[ii];
        const float* wrow = W1 + (size_t)ii * FFD + tid;
#pragma unroll
        for (int u = 0; u < 8; ++u) acc[u] += xv * wrow[u * 256];
    }
    float* o = pmid + ((size_t)rw * 8 + p) * FFD + tid;
#pragma unroll
    for (int u = 0; u < 8; ++u) o[u * 256] = acc[u];
}

__global__ __launch_bounds__(256) void k_fgl2(
    const float* __restrict__ pmid, const float* __restrict__ b1,
    float* __restrict__ mid)
{
    int g = blockIdx.x * 256 + threadIdx.x;
    int e4 = g * 4;
    int rw = e4 >> 11;
    int m = e4 & 2047;
    int isl = rw & 1;
    int idx = isl ? 2 : 0;
#pragma unroll
    for (int d = 0; d < 4; ++d) {
        float s = 0.f;
#pragma unroll
        for (int p = 0; p < 8; ++p)
            s += pmid[((size_t)rw * 8 + p) * FFD + m + d];
        s += b1[idx * FFD + m + d];
        mid[(size_t)rw * FFD + m + d] = gelu(s);
    }
}

__global__ __launch_bounds__(256) void k_fgl3(
    const float* __restrict__ mid, const float* __restrict__ w2,
    float* __restrict__ pout)
{
    __shared__ float ms[256];
    int p = blockIdx.x, rw = blockIdx.y;
    int isl = rw & 1;
    int idx = isl ? 2 : 0;
    int tid = threadIdx.x;
    ms[tid] = mid[(size_t)rw * FFD + p * 256 + tid];
    __syncthreads();
    const float* W2 = w2 + (size_t)idx * FFD * HIDN + (size_t)p * 256 * HIDN;
    float a0 = 0.f, a1 = 0.f;
    for (int mm = 0; mm < 256; ++mm) {
        float mv = ms[mm];
        const float* wrow = W2 + (size_t)mm * HIDN + tid;
        a0 += mv * wrow[0];
        a1 += mv * wrow[256];
    }
    float* o = pout + ((size_t)rw * 8 + p) * HIDN + tid;
    o[0] = a0;
    o[256] = a1;
}

__global__ __launch_bounds__(256) void k_fgl4(
    const float* __restrict__ pout, const float* __restrict__ b2,
    const ushort* __restrict__ nb,
    const float* __restrict__ og, const float* __restrict__ obt,
    float* __restrict__ out)
{
    __shared__ float red[512];
    int rw = blockIdx.x;
    int b = rw >> 1, isl = rw & 1;
    int idx = isl ? 2 : 0;
    size_t nrow = (size_t)b * NNODE + (isl ? SEQ + 1 : 0);
    int tid = threadIdx.x;
    float xv[2], s1 = 0.f, s2 = 0.f;
#pragma unroll
    for (int u = 0; u < 2; ++u) {
        int o = tid + u * 256;
        float s = 0.f;
#pragma unroll
        for (int p = 0; p < 8; ++p)
            s += pout[((size_t)rw * 8 + p) * HIDN + o];
        s += b2[idx * HIDN + o] + bf2f(nb[nrow * HIDN + o]);
        xv[u] = s; s1 += s; s2 += s * s;
    }
    red[tid] = s1;
    __syncthreads();
    for (int s = 128; s; s >>= 1) { if (tid < s) red[tid] += red[tid + s]; __syncthreads(); }
    float mean = red[0] * (1.f / 512.f);
    __syncthreads();
    red[tid] = s2;
    __syncthreads();
    for (int s = 128; s; s >>= 1) { if (tid < s) red[tid] += red[tid + s]; __syncthreads(); }
    float var = red[0] * (1.f / 512.f) - mean * mean; var = fmaxf(var, 0.f);
    float rn = rsqrtf(var + 1e-5f);
    size_t obase = isl ? ((size_t)8192 + (size_t)MTOK * HIDN + (size_t)b * HIDN)
                       : ((size_t)b * HIDN);
#pragma unroll
    for (int u = 0; u < 2; ++u) {
        int o = tid + u * 256;
        out[obase + o] = (xv[u] - mean) * rn * og[idx * HIDN + o] + obt[idx * HIDN + o];
    }
}

// ---------------------------------------------------------------- final token LN: in-place on Pt (fp32), + bias + residual
__global__ __launch_bounds__(64) void k_ln_final(
    float* __restrict__ Pt, const ushort* __restrict__ nb,
    const float* __restrict__ b2,
    const float* __restrict__ gam, const float* __restrict__ bet)
{
    int r = blockIdx.x, lane = threadIdx.x;
    int nrow = r + 2 * (r >> 10) + 1;
    int o0 = lane * 8;
    float* x = Pt + (size_t)r * HIDN + o0;
    const ushort* res = nb + (size_t)nrow * HIDN + o0;
    float v[8], s1 = 0.f, s2 = 0.f;
#pragma unroll
    for (int d = 0; d < 8; ++d) {
        float t = x[d] + b2[o0 + d] + bf2f(res[d]);
        v[d] = t; s1 += t; s2 += t * t;
    }
#pragma unroll
    for (int off = 32; off; off >>= 1) { s1 += __shfl_xor(s1, off); s2 += __shfl_xor(s2, off); }
    float mean = s1 * (1.f / 512.f);
    float var = s2 * (1.f / 512.f) - mean * mean; var = fmaxf(var, 0.f);
    float rn = rsqrtf(var + 1e-5f);
#pragma unroll
    for (int d = 0; d < 8; ++d)
        x[d] = (v[d] - mean) * rn * gam[o0 + d] + bet[o0 + d];
}

// ================================================================ launch
extern "C" void kernel_launch(void* const* d_in, const int* in_sizes, int n_in,
                              void* d_out, int out_size, void* d_ws, size_t ws_size,
                              hipStream_t stream)
{
    (void)in_sizes; (void)n_in; (void)out_size; (void)ws_size;
    const float* g_emb   = (const float*)d_in[0];
    const float* tok_emb = (const float*)d_in[1];
    const float* l_emb   = (const float*)d_in[2];
    const float* am      = (const float*)d_in[3];
    const int*   last    = (const int*)d_in[4];
    const float* gat_W   = (const float*)d_in[5];
    const float* gat_a   = (const float*)d_in[6];
    const float* ln_g    = (const float*)d_in[7];
    const float* ln_b    = (const float*)d_in[8];
    const float* ffn_w1  = (const float*)d_in[9];
    const float* ffn_b1  = (const float*)d_in[10];
    const float* ffn_w2  = (const float*)d_in[11];
    const float* ffn_b2  = (const float*)d_in[12];
    const float* oln_g   = (const float*)d_in[13];
    const float* oln_b   = (const float*)d_in[14];
    float* out = (float*)d_out;

    // workspace ~31 MiB (proven budget 33.1). all regions written before read.
    char* w = (char*)d_ws;
    ushort* nodes_b = (ushort*)w; w += (size_t)MPAD * HIDN * 2;      // 16.9 MB
    char*   scratch = w;          w += (size_t)MTOK * NCH * 2;       //  8.4 MB (Hmid chunk / gl+fgl scratch)
    ushort* w1t     = (ushort*)w; w += (size_t)FFD * HIDN * 2;       //  2.1 MB
    ushort* w2t     = (ushort*)w; w += (size_t)FFD * HIDN * 2;       //  2.1 MB
    ushort* gatWb   = (ushort*)w; w += (size_t)2 * HIDN * HIDN * 2;  //  1.0 MB
    float*  sqb     = (float*)w;  w += (size_t)MPAD * 4 * 4;         //  0.26 MB
    float*  skb     = (float*)w;  w += (size_t)MPAD * 4 * 4;         //  0.26 MB

    ushort* Hmid = (ushort*)scratch;                  // token-FFN mid chunk (16384 x 256 bf16)
    // g/l FFN scratch (first 2.75 MB of scratch; used post-layers, pre-token-FFN)
    float* pmid = (float*)scratch;                    // 32*8*2048 f32 = 2 MB
    float* mid  = pmid + (size_t)32 * 8 * FFD;        // 256 KB
    float* pout = mid + (size_t)32 * FFD;             // 512 KB
    // g/l attention scratch (at scratch + 3 MB; used during layers)
    float* ebuf  = (float*)(scratch + (size_t)3 * 1024 * 1024);  // 513 KB
    float* einv  = ebuf + (size_t)32 * NNODE * 4;
    float* pout2 = einv + 128;                                   // 576 KB

    // P (node projections, MROWS x 512 fp32) aliases d_out (dead before outputs).
    float* P  = out;
    // Token FFN2 fp32 accumulator = final token output region (exactly MTOK x 512).
    float* Pt = out + 8192;

    k_build_nodes<<<MPAD * HIDN / 256, 256, 0, stream>>>(g_emb, tok_emb, l_emb, nodes_b);
    k_cvt<<<(2 * HIDN * HIDN) / 256, 256, 0, stream>>>(gat_W, gatWb, 2 * HIDN * HIDN);
    k_transpose<<<dim3(FFD / 32, HIDN / 32), dim3(32, 8), 0, stream>>>(ffn_w1 + (size_t)HIDN * FFD, w1t, HIDN, FFD);
    k_transpose<<<dim3(HIDN / 32, FFD / 32), dim3(32, 8), 0, stream>>>(ffn_w2 + (size_t)FFD * HIDN, w2t, FFD, HIDN);

    for (int k = 0; k < 2; ++k) {
        k_gemm_bt<<<dim3(HIDN / BN, MPAD / BM), 256, 0, stream>>>(
            nodes_b, gatWb + (size_t)k * HIDN * HIDN, P, nullptr, nullptr,
            HIDN, HIDN, HIDN, /*mode*/0, /*amap*/0, MROWS, /*first*/1);
        k_sqsk<<<MROWS / 4, 256, 0, stream>>>(P, gat_a + k * NHEAD * 2 * DHEAD, sqb, skb);
        k_attn_token<<<MTOK, 64, 0, stream>>>(P, sqb, skb, am, last,
                                              ln_g + k * HIDN, ln_b + k * HIDN, nodes_b);
        k_glsm<<<32, 256, 0, stream>>>(sqb, skb, last, ebuf, einv);
        k_glpv<<<dim3(9, 32), 256, 0, stream>>>(P, ebuf, pout2);
        k_glred<<<32, 256, 0, stream>>>(pout2, einv, ln_g + k * HIDN, ln_b + k * HIDN, nodes_b);
    }

    // g/l FFN (parallel split) — P (= d_out) dead from here.
    k_fgl1<<<dim3(8, 32), 256, 0, stream>>>(nodes_b, ffn_w1, pmid);
    k_fgl2<<<64, 256, 0, stream>>>(pmid, ffn_b1, mid);
    k_fgl3<<<dim3(8, 32), 256, 0, stream>>>(mid, ffn_w2, pout);
    k_fgl4<<<32, 256, 0, stream>>>(pout, ffn_b2, nodes_b, oln_g, oln_b, out);

    // token FFN: 8 mid-col chunks; FFN2 accumulates fp32 into Pt (token out region)
    for (int c = 0; c < FFD / NCH; ++c) {
        k_gemm_bt<<<dim3(NCH / BN, MTOK / BM), 256, 0, stream>>>(
            nodes_b, w1t + (size_t)c * NCH * HIDN, nullptr, Hmid,
            ffn_b1 + FFD + c * NCH, NCH, HIDN, HIDN, /*mode*/1, /*amap*/1, MTOK, 1);
        k_gemm_bt<<<dim3(HIDN / BN, MTOK / BM), 256, 0, stream>>>(
            Hmid, w2t + (size_t)c * NCH, Pt, nullptr, nullptr,
            HIDN, NCH, FFD, /*mode*/0, /*amap*/0, MTOK, /*first*/(c == 0) ? 1 : 0);
    }
    k_ln_final<<<MTOK, 64, 0, stream>>>(Pt, nodes_b, ffn_b2 + HIDN, oln_g + HIDN, oln_b + HIDN);
}

// Round 8
// 799.824 us; speedup vs baseline: 1.9457x; 1.0906x over previous
//
#include <hip/hip_runtime.h>
#include <stdint.h>
#include <math.h>

#define HIDN 512
#define NHEAD 4
#define DHEAD 128
#define BATCH 16
#define SEQ 1024
#define NNODE 1026
#define MROWS (BATCH * NNODE)   // 16416
#define MPAD 16512              // 129 * 128
#define MTOK (BATCH * SEQ)      // 16384
#define FFD 2048
#define NCH 256                 // FFN mid-col chunk (8 chunks)
#define JCH 114                 // gl-attn j-chunk (9 * 114 = 1026)

typedef short bf16x8 __attribute__((ext_vector_type(8)));
typedef float f32x4 __attribute__((ext_vector_type(4)));

__device__ __forceinline__ float bf2f(ushort u) {
    union { uint32_t i; float f; } v; v.i = ((uint32_t)u) << 16; return v.f;
}
__device__ __forceinline__ ushort f2bf(float f) {
    uint32_t x = __float_as_uint(f);
    return (ushort)((x + 0x7fffu + ((x >> 16) & 1u)) >> 16);
}
__device__ __forceinline__ float gelu(float v) {
    return 0.5f * v * (1.f + erff(v * 0.70710678118654752f));
}
// swizzled index into 64x128 f32 epilogue tile (float4-granular XOR)
__device__ __forceinline__ int cswz(int row, int col) {
    return row * 128 + ((((col >> 2) ^ (row & 7)) & 31) << 2) + (col & 3);
}

// ---------------------------------------------------------------- build nodes: fp32 in -> bf16 node buffer
__global__ __launch_bounds__(256) void k_build_nodes(
    const float* __restrict__ g, const float* __restrict__ tok,
    const float* __restrict__ l, ushort* __restrict__ nb)
{
    int idx = blockIdx.x * 256 + threadIdx.x;       // MPAD*HIDN total
    int r = idx >> 9, c = idx & 511;
    float u = 0.f;
    if (r < MROWS) {
        int b = r / NNODE;
        int n = r - b * NNODE;
        if (n == 0)            u = g[b * HIDN + c];
        else if (n <= SEQ)     u = tok[((size_t)b * SEQ + (n - 1)) * HIDN + c];
        else                   u = l[b * HIDN + c];
    }
    nb[idx] = f2bf(u);
}

// ---------------------------------------------------------------- fp32 -> bf16 flat convert
__global__ __launch_bounds__(256) void k_cvt(
    const float* __restrict__ in, ushort* __restrict__ out, int n)
{
    int idx = blockIdx.x * 256 + threadIdx.x;
    if (idx < n) out[idx] = f2bf(in[idx]);
}

// ---------------------------------------------------------------- transpose fp32 -> bf16
__global__ __launch_bounds__(256) void k_transpose(
    const float* __restrict__ in, ushort* __restrict__ out, int R, int C)
{
    __shared__ float t[32][33];
    int x = blockIdx.x * 32 + threadIdx.x;
    int y0 = blockIdx.y * 32;
    for (int dy = threadIdx.y; dy < 32; dy += 8)
        t[dy][threadIdx.x] = in[(size_t)(y0 + dy) * C + x];
    __syncthreads();
    int ox = y0 + threadIdx.x;
    int oy0 = blockIdx.x * 32;
    for (int dy = threadIdx.y; dy < 32; dy += 8)
        out[(size_t)(oy0 + dy) * R + ox] = f2bf(t[threadIdx.x][dy]);
}

// ---------------------------------------------------------------- MFMA GEMM (A: rowmaj MxK bf16 lda=K, Bt: NxK rowmaj bf16, ldb free)
// mode 1: Cb bf16 = gelu(A*B + bias)
// mode 3: Cb bf16 = A*B
// else  : Cf fp32 = A*B  (first=1) or Cf += A*B (first=0)
// amap: A row gm remapped token->node row
#define BM 128
#define BN 128
#define BK 64

__global__ __launch_bounds__(256) void k_gemm_bt(
    const ushort* __restrict__ A, const ushort* __restrict__ Bt,
    float* __restrict__ Cf, ushort* __restrict__ Cb,
    const float* __restrict__ bias,
    int N, int K, int ldb, int mode, int amap, int mguard, int first)
{
    __shared__ ushort smem[BM * BK + BN * BK];   // 32 KB
    ushort* sA = smem;
    ushort* sB = smem + BM * BK;
    int tid = threadIdx.x;
    int lane = tid & 63;
    int wave = tid >> 6;
    int wm = wave >> 1, wn = wave & 1;
    int m0 = blockIdx.y * BM;
    int n0 = blockIdx.x * BN;

    f32x4 acc[4][4];
#pragma unroll
    for (int i = 0; i < 4; ++i)
#pragma unroll
        for (int j = 0; j < 4; ++j) acc[i][j] = (f32x4){0.f, 0.f, 0.f, 0.f};

    int lr = lane >> 3;              // row within 8-row chunk
    int gco = ((lane & 7) ^ lr) * 8; // XOR-swizzled col-chunk offset (elements)

    for (int k0 = 0; k0 < K; k0 += BK) {
#pragma unroll
        for (int t = 0; t < 4; ++t) {
            int q = wave * 4 + t;            // 0..15 : 8-row chunk id
            int rr8 = q * 8 + lr;
            int grA = m0 + rr8;
            if (amap) grA = grA + 2 * (grA >> 10) + 1;
            const ushort* gpA = A + (size_t)grA * K + (k0 + gco);
            __builtin_amdgcn_global_load_lds(
                (const __attribute__((address_space(1))) void*)gpA,
                (__attribute__((address_space(3))) void*)&sA[q * 512], 16, 0, 0);
            int grB = n0 + rr8;
            const ushort* gpB = Bt + (size_t)grB * ldb + (k0 + gco);
            __builtin_amdgcn_global_load_lds(
                (const __attribute__((address_space(1))) void*)gpB,
                (__attribute__((address_space(3))) void*)&sB[q * 512], 16, 0, 0);
        }
        __syncthreads();
        int rr = lane & 7;
        int rhi = (lane & 15) >> 3;
#pragma unroll
        for (int kk = 0; kk < BK; kk += 32) {
            int c4 = (kk >> 3) + (lane >> 4);          // col-chunk 0..7
            int swz = rr * 64 + ((c4 ^ rr) << 3);
            bf16x8 af[4], bfr[4];
#pragma unroll
            for (int i = 0; i < 4; ++i)
                af[i] = *reinterpret_cast<const bf16x8*>(&sA[(wm * 8 + i * 2 + rhi) * 512 + swz]);
#pragma unroll
            for (int j = 0; j < 4; ++j)
                bfr[j] = *reinterpret_cast<const bf16x8*>(&sB[(wn * 8 + j * 2 + rhi) * 512 + swz]);
#pragma unroll
            for (int i = 0; i < 4; ++i)
#pragma unroll
                for (int j = 0; j < 4; ++j)
                    acc[i][j] = __builtin_amdgcn_mfma_f32_16x16x32_bf16(af[i], bfr[j], acc[i][j], 0, 0, 0);
        }
        __syncthreads();
    }

    // -------- coalesced epilogue: 2 passes of 64 rows via LDS f32 tile
    float* sC = (float*)smem;        // 64 x 128 f32 = 32 KB
    int rb = (lane >> 4) * 4;
    int cb = lane & 15;
    int lrow = tid >> 2;             // 0..63
    int lcol = (tid & 3) << 5;       // 0,32,64,96
#pragma unroll
    for (int pass = 0; pass < 2; ++pass) {
        if (wm == pass) {
#pragma unroll
            for (int i = 0; i < 4; ++i)
#pragma unroll
                for (int j = 0; j < 4; ++j)
#pragma unroll
                    for (int rg = 0; rg < 4; ++rg)
                        sC[cswz(i * 16 + rb + rg, wn * 64 + j * 16 + cb)] = acc[i][j][rg];
        }
        __syncthreads();
        int gm = m0 + pass * 64 + lrow;
        if (gm < mguard) {
            int gn0 = n0 + lcol;
            float v[32];
#pragma unroll
            for (int e4 = 0; e4 < 8; ++e4) {
                float4 t = *(const float4*)&sC[cswz(lrow, lcol + e4 * 4)];
                v[e4 * 4 + 0] = t.x; v[e4 * 4 + 1] = t.y;
                v[e4 * 4 + 2] = t.z; v[e4 * 4 + 3] = t.w;
            }
            if (mode == 1 || mode == 3) {
                uint4* dst = (uint4*)(Cb + (size_t)gm * N + gn0);
#pragma unroll
                for (int q2 = 0; q2 < 4; ++q2) {
                    float s[8];
#pragma unroll
                    for (int t = 0; t < 8; ++t) {
                        float x = v[q2 * 8 + t];
                        s[t] = (mode == 1) ? gelu(x + bias[gn0 + q2 * 8 + t]) : x;
                    }
                    uint4 w;
                    w.x = (uint32_t)f2bf(s[0]) | ((uint32_t)f2bf(s[1]) << 16);
                    w.y = (uint32_t)f2bf(s[2]) | ((uint32_t)f2bf(s[3]) << 16);
                    w.z = (uint32_t)f2bf(s[4]) | ((uint32_t)f2bf(s[5]) << 16);
                    w.w = (uint32_t)f2bf(s[6]) | ((uint32_t)f2bf(s[7]) << 16);
                    dst[q2] = w;
                }
            } else {
                float4* dst = (float4*)(Cf + (size_t)gm * N + gn0);
#pragma unroll
                for (int e4 = 0; e4 < 8; ++e4) {
                    float4 t;
                    t.x = v[e4 * 4 + 0]; t.y = v[e4 * 4 + 1];
                    t.z = v[e4 * 4 + 2]; t.w = v[e4 * 4 + 3];
                    if (!first) {
                        float4 o = dst[e4];
                        t.x += o.x; t.y += o.y; t.z += o.z; t.w += o.w;
                    }
                    dst[e4] = t;
                }
            }
        }
        __syncthreads();
    }
}

// ---------------------------------------------------------------- sq/sk per node row (P bf16, a fp32)
__global__ __launch_bounds__(256) void k_sqsk(
    const ushort* __restrict__ P, const float* __restrict__ a,
    float* __restrict__ sq, float* __restrict__ sk)
{
    int wave = threadIdx.x >> 6, lane = threadIdx.x & 63;
    int row = blockIdx.x * 4 + wave;
    if (row >= MROWS) return;
    int hh = lane >> 4;
    int o0 = lane * 8;
    int dl = o0 & 127;
    const ushort* p = P + (size_t)row * HIDN + o0;
    const float* a1 = a + hh * 256 + dl;
    const float* a2 = a1 + 128;
    float s1 = 0.f, s2 = 0.f;
#pragma unroll
    for (int d = 0; d < 8; ++d) {
        float pv = bf2f(p[d]);
        s1 += pv * a1[d];
        s2 += pv * a2[d];
    }
#pragma unroll
    for (int off = 8; off; off >>= 1) {
        s1 += __shfl_xor(s1, off);
        s2 += __shfl_xor(s2, off);
    }
    if ((lane & 15) == 0) {
        sq[row * 4 + hh] = s1;
        sk[row * 4 + hh] = s2;
    }
}

// ---------------------------------------------------------------- token attention + elu + residual + LN (1 wave / token)
// XCD swizzle: tok = (bid&7)*2048 + (bid>>3) — contiguous 2048-token span per XCD
__global__ __launch_bounds__(64) void k_attn_token(
    const ushort* __restrict__ P, const float* __restrict__ sq, const float* __restrict__ sk,
    const float* __restrict__ am, const int* __restrict__ last,
    const float* __restrict__ gam, const float* __restrict__ bet,
    ushort* __restrict__ nb)
{
    int bid = blockIdx.x;
    int tokid = ((bid & 7) << 11) | (bid >> 3);
    int b = tokid >> 10, i = tokid & 1023;
    int lane = threadIdx.x;
    int hh = lane >> 4;
    int base = b * NNODE;
    int qrow = base + 1 + i;

    int kr[13];
    int val[13];
    int rowok = am[b * SEQ + i] > 0.f ? 1 : 0;
    kr[0] = base; val[0] = rowok;
#pragma unroll
    for (int s = 0; s < 11; ++s) {
        int t = i - 5 + s;
        int inb = (t >= 0) && (t <= SEQ - 1);
        int tt = inb ? t : 0;
        int v = inb && rowok && (am[b * SEQ + tt] > 0.f);
        kr[1 + s] = base + 1 + tt;
        val[1 + s] = v;
    }
    kr[12] = base + SEQ + 1;
    val[12] = (rowok && (i >= last[b])) ? 1 : 0;

    float sqv = sq[qrow * 4 + hh];
    float sc[13];
    float mx = -1e30f;
#pragma unroll
    for (int t = 0; t < 13; ++t) {
        float s = 0.f;
        if (val[t]) {
            s = sqv + sk[kr[t] * 4 + hh];
            s = s >= 0.f ? s : 0.2f * s;
            mx = fmaxf(mx, s);
        }
        sc[t] = s;
    }
    float den = 0.f;
#pragma unroll
    for (int t = 0; t < 13; ++t) {
        float ev = 0.f;
        if (val[t]) ev = expf(sc[t] - mx);
        sc[t] = ev; den += ev;
    }
    float inv = (den > 1e-30f && den < 1e30f) ? 1.f / den : 0.f;

    int o0 = lane * 8;
    float accv[8] = {0.f, 0.f, 0.f, 0.f, 0.f, 0.f, 0.f, 0.f};
#pragma unroll
    for (int t = 0; t < 13; ++t) {
        if (val[t]) {
            float wgt = sc[t] * inv;
            const ushort* pv = P + (size_t)kr[t] * HIDN + o0;
#pragma unroll
            for (int d = 0; d < 8; ++d) accv[d] += wgt * bf2f(pv[d]);
        }
    }

    ushort* nrow = nb + (size_t)qrow * HIDN + o0;
    float x[8], s1 = 0.f, s2 = 0.f;
#pragma unroll
    for (int d = 0; d < 8; ++d) {
        float v = accv[d];
        v = v > 0.f ? v : expf(v) - 1.f;   // elu
        v += bf2f(nrow[d]);                // residual
        x[d] = v; s1 += v; s2 += v * v;
    }
#pragma unroll
    for (int off = 32; off; off >>= 1) { s1 += __shfl_xor(s1, off); s2 += __shfl_xor(s2, off); }
    float mean = s1 * (1.f / 512.f);
    float var = s2 * (1.f / 512.f) - mean * mean; var = fmaxf(var, 0.f);
    float rn = rsqrtf(var + 1e-5f);
#pragma unroll
    for (int d = 0; d < 8; ++d) {
        float y = (x[d] - mean) * rn * gam[o0 + d] + bet[o0 + d];
        nrow[d] = f2bf(y);
    }
}

// ---------------------------------------------------------------- g/l attention, split version
__global__ __launch_bounds__(256) void k_glsm(
    const float* __restrict__ sq, const float* __restrict__ sk,
    const int* __restrict__ last,
    float* __restrict__ ebuf, float* __restrict__ einv)
{
    __shared__ float red[1024];
    int rw = blockIdx.x, b = rw >> 1, isl = rw & 1;
    int base = b * NNODE;
    int qrow = base + (isl ? (SEQ + 1) : 0);
    int lastb = last[b];
    int tid = threadIdx.x;

    float sqh[4];
#pragma unroll
    for (int h = 0; h < 4; ++h) sqh[h] = sq[qrow * 4 + h];

    float mx[4] = {-1e30f, -1e30f, -1e30f, -1e30f};
    for (int j = tid; j < NNODE; j += 256) {
        bool ok = !isl || (j == 0 || j == SEQ + 1 || (j >= lastb + 1 && j <= SEQ));
        if (ok) {
#pragma unroll
            for (int h = 0; h < 4; ++h) {
                float s = sqh[h] + sk[(base + j) * 4 + h];
                s = s >= 0.f ? s : 0.2f * s;
                mx[h] = fmaxf(mx[h], s);
            }
        }
    }
#pragma unroll
    for (int h = 0; h < 4; ++h) red[tid * 4 + h] = mx[h];
    __syncthreads();
    for (int s = 128; s; s >>= 1) {
        if (tid < s) {
#pragma unroll
            for (int h = 0; h < 4; ++h)
                red[tid * 4 + h] = fmaxf(red[tid * 4 + h], red[(tid + s) * 4 + h]);
        }
        __syncthreads();
    }
#pragma unroll
    for (int h = 0; h < 4; ++h) mx[h] = red[h];
    __syncthreads();

    float sm[4] = {0.f, 0.f, 0.f, 0.f};
    for (int j = tid; j < NNODE; j += 256) {
        bool ok = !isl || (j == 0 || j == SEQ + 1 || (j >= lastb + 1 && j <= SEQ));
#pragma unroll
        for (int h = 0; h < 4; ++h) {
            float v = 0.f;
            if (ok) {
                float s = sqh[h] + sk[(base + j) * 4 + h];
                s = s >= 0.f ? s : 0.2f * s;
                v = expf(s - mx[h]);
            }
            ebuf[((size_t)rw * NNODE + j) * 4 + h] = v;
            sm[h] += v;
        }
    }
#pragma unroll
    for (int h = 0; h < 4; ++h) red[tid * 4 + h] = sm[h];
    __syncthreads();
    for (int s = 128; s; s >>= 1) {
        if (tid < s) {
#pragma unroll
            for (int h = 0; h < 4; ++h) red[tid * 4 + h] += red[(tid + s) * 4 + h];
        }
        __syncthreads();
    }
    if (tid < 4) {
        float den = red[tid];
        einv[rw * 4 + tid] = (den > 1e-30f && den < 1e30f) ? 1.f / den : 0.f;
    }
}

__global__ __launch_bounds__(256) void k_glpv(
    const ushort* __restrict__ P, const float* __restrict__ ebuf,
    float* __restrict__ pout2)
{
    __shared__ float es[JCH * 4];
    int p = blockIdx.x, rw = blockIdx.y;
    int b = rw >> 1;
    int base = b * NNODE;
    int tid = threadIdx.x;
    for (int t = tid; t < JCH * 4; t += 256)
        es[t] = ebuf[((size_t)rw * NNODE + p * JCH) * 4 + t];
    __syncthreads();
    int o0 = tid, o1 = tid + 256;
    int h0 = o0 >> 7, h1 = o1 >> 7;
    const ushort* Pb = P + (size_t)(base + p * JCH) * HIDN;
    float a0 = 0.f, a1 = 0.f;
    for (int j = 0; j < JCH; ++j) {
        const ushort* pr = Pb + (size_t)j * HIDN;
        a0 += es[j * 4 + h0] * bf2f(pr[o0]);
        a1 += es[j * 4 + h1] * bf2f(pr[o1]);
    }
    float* o = pout2 + ((size_t)rw * 9 + p) * HIDN;
    o[o0] = a0;
    o[o1] = a1;
}

__global__ __launch_bounds__(256) void k_glred(
    const float* __restrict__ pout2, const float* __restrict__ einv,
    const float* __restrict__ gam, const float* __restrict__ bet,
    ushort* __restrict__ nb)
{
    __shared__ float red[512];
    int rw = blockIdx.x, b = rw >> 1, isl = rw & 1;
    size_t qrow = (size_t)b * NNODE + (isl ? SEQ + 1 : 0);
    int tid = threadIdx.x;
    float xv[2], s1 = 0.f, s2 = 0.f;
#pragma unroll
    for (int u = 0; u < 2; ++u) {
        int o = tid + u * 256;
        int h = o >> 7;
        float acc = 0.f;
#pragma unroll
        for (int p = 0; p < 9; ++p)
            acc += pout2[((size_t)rw * 9 + p) * HIDN + o];
        acc *= einv[rw * 4 + h];
        float v = acc > 0.f ? acc : expf(acc) - 1.f;
        v += bf2f(nb[qrow * HIDN + o]);
        xv[u] = v; s1 += v; s2 += v * v;
    }
    red[tid] = s1;
    __syncthreads();
    for (int s = 128; s; s >>= 1) { if (tid < s) red[tid] += red[tid + s]; __syncthreads(); }
    float mean = red[0] * (1.f / 512.f);
    __syncthreads();
    red[tid] = s2;
    __syncthreads();
    for (int s = 128; s; s >>= 1) { if (tid < s) red[tid] += red[tid + s]; __syncthreads(); }
    float var = red[0] * (1.f / 512.f) - mean * mean; var = fmaxf(var, 0.f);
    float rn = rsqrtf(var + 1e-5f);
#pragma unroll
    for (int u = 0; u < 2; ++u) {
        int o = tid + u * 256;
        float y = (xv[u] - mean) * rn * gam[o] + bet[o];
        nb[qrow * HIDN + o] = f2bf(y);
    }
}

// ---------------------------------------------------------------- g/l FFN, parallel split version
__global__ __launch_bounds__(256) void k_fgl1(
    const ushort* __restrict__ nb, const float* __restrict__ w1,
    float* __restrict__ pmid)
{
    __shared__ float xs[64];
    int p = blockIdx.x, rw = blockIdx.y;
    int b = rw >> 1, isl = rw & 1;
    int idx = isl ? 2 : 0;
    size_t nrow = (size_t)b * NNODE + (isl ? SEQ + 1 : 0);
    int tid = threadIdx.x;
    if (tid < 64) xs[tid] = bf2f(nb[nrow * HIDN + p * 64 + tid]);
    __syncthreads();
    const float* W1 = w1 + (size_t)idx * HIDN * FFD + (size_t)p * 64 * FFD;
    float acc[8] = {0.f, 0.f, 0.f, 0.f, 0.f, 0.f, 0.f, 0.f};
    for (int ii = 0; ii < 64; ++ii) {
        float xv = xs[ii];
        const float* wrow = W1 + (size_t)ii * FFD + tid;
#pragma unroll
        for (int u = 0; u < 8; ++u) acc[u] += xv * wrow[u * 256];
    }
    float* o = pmid + ((size_t)rw * 8 + p) * FFD + tid;
#pragma unroll
    for (int u = 0; u < 8; ++u) o[u * 256] = acc[u];
}

__global__ __launch_bounds__(256) void k_fgl2(
    const float* __restrict__ pmid, const float* __restrict__ b1,
    float* __restrict__ mid)
{
    int g = blockIdx.x * 256 + threadIdx.x;
    int e4 = g * 4;
    int rw = e4 >> 11;
    int m = e4 & 2047;
    int isl = rw & 1;
    int idx = isl ? 2 : 0;
#pragma unroll
    for (int d = 0; d < 4; ++d) {
        float s = 0.f;
#pragma unroll
        for (int p = 0; p < 8; ++p)
            s += pmid[((size_t)rw * 8 + p) * FFD + m + d];
        s += b1[idx * FFD + m + d];
        mid[(size_t)rw * FFD + m + d] = gelu(s);
    }
}

__global__ __launch_bounds__(256) void k_fgl3(
    const float* __restrict__ mid, const float* __restrict__ w2,
    float* __restrict__ pout)
{
    __shared__ float ms[256];
    int p = blockIdx.x, rw = blockIdx.y;
    int isl = rw & 1;
    int idx = isl ? 2 : 0;
    int tid = threadIdx.x;
    ms[tid] = mid[(size_t)rw * FFD + p * 256 + tid];
    __syncthreads();
    const float* W2 = w2 + (size_t)idx * FFD * HIDN + (size_t)p * 256 * HIDN;
    float a0 = 0.f, a1 = 0.f;
    for (int mm = 0; mm < 256; ++mm) {
        float mv = ms[mm];
        const float* wrow = W2 + (size_t)mm * HIDN + tid;
        a0 += mv * wrow[0];
        a1 += mv * wrow[256];
    }
    float* o = pout + ((size_t)rw * 8 + p) * HIDN + tid;
    o[0] = a0;
    o[256] = a1;
}

__global__ __launch_bounds__(256) void k_fgl4(
    const float* __restrict__ pout, const float* __restrict__ b2,
    const ushort* __restrict__ nb,
    const float* __restrict__ og, const float* __restrict__ obt,
    float* __restrict__ out)
{
    __shared__ float red[512];
    int rw = blockIdx.x;
    int b = rw >> 1, isl = rw & 1;
    int idx = isl ? 2 : 0;
    size_t nrow = (size_t)b * NNODE + (isl ? SEQ + 1 : 0);
    int tid = threadIdx.x;
    float xv[2], s1 = 0.f, s2 = 0.f;
#pragma unroll
    for (int u = 0; u < 2; ++u) {
        int o = tid + u * 256;
        float s = 0.f;
#pragma unroll
        for (int p = 0; p < 8; ++p)
            s += pout[((size_t)rw * 8 + p) * HIDN + o];
        s += b2[idx * HIDN + o] + bf2f(nb[nrow * HIDN + o]);
        xv[u] = s; s1 += s; s2 += s * s;
    }
    red[tid] = s1;
    __syncthreads();
    for (int s = 128; s; s >>= 1) { if (tid < s) red[tid] += red[tid + s]; __syncthreads(); }
    float mean = red[0] * (1.f / 512.f);
    __syncthreads();
    red[tid] = s2;
    __syncthreads();
    for (int s = 128; s; s >>= 1) { if (tid < s) red[tid] += red[tid + s]; __syncthreads(); }
    float var = red[0] * (1.f / 512.f) - mean * mean; var = fmaxf(var, 0.f);
    float rn = rsqrtf(var + 1e-5f);
    size_t obase = isl ? ((size_t)8192 + (size_t)MTOK * HIDN + (size_t)b * HIDN)
                       : ((size_t)b * HIDN);
#pragma unroll
    for (int u = 0; u < 2; ++u) {
        int o = tid + u * 256;
        out[obase + o] = (xv[u] - mean) * rn * og[idx * HIDN + o] + obt[idx * HIDN + o];
    }
}

// ---------------------------------------------------------------- final token LN: in-place on Pt (fp32), + bias + residual
__global__ __launch_bounds__(64) void k_ln_final(
    float* __restrict__ Pt, const ushort* __restrict__ nb,
    const float* __restrict__ b2,
    const float* __restrict__ gam, const float* __restrict__ bet)
{
    int r = blockIdx.x, lane = threadIdx.x;
    int nrow = r + 2 * (r >> 10) + 1;
    int o0 = lane * 8;
    float* x = Pt + (size_t)r * HIDN + o0;
    const ushort* res = nb + (size_t)nrow * HIDN + o0;
    float v[8], s1 = 0.f, s2 = 0.f;
#pragma unroll
    for (int d = 0; d < 8; ++d) {
        float t = x[d] + b2[o0 + d] + bf2f(res[d]);
        v[d] = t; s1 += t; s2 += t * t;
    }
#pragma unroll
    for (int off = 32; off; off >>= 1) { s1 += __shfl_xor(s1, off); s2 += __shfl_xor(s2, off); }
    float mean = s1 * (1.f / 512.f);
    float var = s2 * (1.f / 512.f) - mean * mean; var = fmaxf(var, 0.f);
    float rn = rsqrtf(var + 1e-5f);
#pragma unroll
    for (int d = 0; d < 8; ++d)
        x[d] = (v[d] - mean) * rn * gam[o0 + d] + bet[o0 + d];
}

// ================================================================ launch
extern "C" void kernel_launch(void* const* d_in, const int* in_sizes, int n_in,
                              void* d_out, int out_size, void* d_ws, size_t ws_size,
                              hipStream_t stream)
{
    (void)in_sizes; (void)n_in; (void)out_size; (void)ws_size;
    const float* g_emb   = (const float*)d_in[0];
    const float* tok_emb = (const float*)d_in[1];
    const float* l_emb   = (const float*)d_in[2];
    const float* am      = (const float*)d_in[3];
    const int*   last    = (const int*)d_in[4];
    const float* gat_W   = (const float*)d_in[5];
    const float* gat_a   = (const float*)d_in[6];
    const float* ln_g    = (const float*)d_in[7];
    const float* ln_b    = (const float*)d_in[8];
    const float* ffn_w1  = (const float*)d_in[9];
    const float* ffn_b1  = (const float*)d_in[10];
    const float* ffn_w2  = (const float*)d_in[11];
    const float* ffn_b2  = (const float*)d_in[12];
    const float* oln_g   = (const float*)d_in[13];
    const float* oln_b   = (const float*)d_in[14];
    float* out = (float*)d_out;

    // workspace ~31 MiB. all regions written before read.
    char* w = (char*)d_ws;
    ushort* nodes_b = (ushort*)w; w += (size_t)MPAD * HIDN * 2;      // 16.9 MB
    char*   scratch = w;          w += (size_t)MTOK * NCH * 2;       //  8.4 MB
    ushort* w1t     = (ushort*)w; w += (size_t)FFD * HIDN * 2;       //  2.1 MB
    ushort* w2t     = (ushort*)w; w += (size_t)FFD * HIDN * 2;       //  2.1 MB
    ushort* gatWb   = (ushort*)w; w += (size_t)2 * HIDN * HIDN * 2;  //  1.0 MB
    float*  sqb     = (float*)w;  w += (size_t)MPAD * 4 * 4;         //  0.26 MB
    float*  skb     = (float*)w;  w += (size_t)MPAD * 4 * 4;         //  0.26 MB

    ushort* Hmid = (ushort*)scratch;                  // token-FFN mid chunk (16384 x 256 bf16)
    // g/l FFN scratch (first 2.75 MB of scratch; post-layers, pre-token-FFN)
    float* pmid = (float*)scratch;
    float* mid  = pmid + (size_t)32 * 8 * FFD;
    float* pout = mid + (size_t)32 * FFD;
    // g/l attention scratch (at scratch + 3 MB; during layers)
    float* ebuf  = (float*)(scratch + (size_t)3 * 1024 * 1024);
    float* einv  = ebuf + (size_t)32 * NNODE * 4;
    float* pout2 = einv + 128;

    // P (node projections, MROWS x 512 bf16, 16.8 MB) aliases d_out (dead
    // before outputs are written).
    ushort* P = (ushort*)out;
    // Token FFN2 fp32 accumulator = final token output region.
    float* Pt = out + 8192;

    k_build_nodes<<<MPAD * HIDN / 256, 256, 0, stream>>>(g_emb, tok_emb, l_emb, nodes_b);
    k_cvt<<<(2 * HIDN * HIDN) / 256, 256, 0, stream>>>(gat_W, gatWb, 2 * HIDN * HIDN);
    k_transpose<<<dim3(FFD / 32, HIDN / 32), dim3(32, 8), 0, stream>>>(ffn_w1 + (size_t)HIDN * FFD, w1t, HIDN, FFD);
    k_transpose<<<dim3(HIDN / 32, FFD / 32), dim3(32, 8), 0, stream>>>(ffn_w2 + (size_t)FFD * HIDN, w2t, FFD, HIDN);

    for (int k = 0; k < 2; ++k) {
        k_gemm_bt<<<dim3(HIDN / BN, MPAD / BM), 256, 0, stream>>>(
            nodes_b, gatWb + (size_t)k * HIDN * HIDN, nullptr, P, nullptr,
            HIDN, HIDN, HIDN, /*mode*/3, /*amap*/0, MROWS, /*first*/1);
        k_sqsk<<<MROWS / 4, 256, 0, stream>>>(P, gat_a + k * NHEAD * 2 * DHEAD, sqb, skb);
        k_attn_token<<<MTOK, 64, 0, stream>>>(P, sqb, skb, am, last,
                                              ln_g + k * HIDN, ln_b + k * HIDN, nodes_b);
        k_glsm<<<32, 256, 0, stream>>>(sqb, skb, last, ebuf, einv);
        k_glpv<<<dim3(9, 32), 256, 0, stream>>>(P, ebuf, pout2);
        k_glred<<<32, 256, 0, stream>>>(pout2, einv, ln_g + k * HIDN, ln_b + k * HIDN, nodes_b);
    }

    // g/l FFN (parallel split) — P (= d_out) dead from here.
    k_fgl1<<<dim3(8, 32), 256, 0, stream>>>(nodes_b, ffn_w1, pmid);
    k_fgl2<<<64, 256, 0, stream>>>(pmid, ffn_b1, mid);
    k_fgl3<<<dim3(8, 32), 256, 0, stream>>>(mid, ffn_w2, pout);
    k_fgl4<<<32, 256, 0, stream>>>(pout, ffn_b2, nodes_b, oln_g, oln_b, out);

    // token FFN: 8 mid-col chunks; FFN2 accumulates fp32 into Pt
    for (int c = 0; c < FFD / NCH; ++c) {
        k_gemm_bt<<<dim3(NCH / BN, MTOK / BM), 256, 0, stream>>>(
            nodes_b, w1t + (size_t)c * NCH * HIDN, nullptr, Hmid,
            ffn_b1 + FFD + c * NCH, NCH, HIDN, HIDN, /*mode*/1, /*amap*/1, MTOK, 1);
        k_gemm_bt<<<dim3(HIDN / BN, MTOK / BM), 256, 0, stream>>>(
            Hmid, w2t + (size_t)c * NCH, Pt, nullptr, nullptr,
            HIDN, NCH, FFD, /*mode*/0, /*amap*/0, MTOK, /*first*/(c == 0) ? 1 : 0);
    }
    k_ln_final<<<MTOK, 64, 0, stream>>>(Pt, nodes_b, ffn_b2 + HIDN, oln_g + HIDN, oln_b + HIDN);
}